// Round 13
// baseline (105.528 us; speedup 1.0000x reference)
//
#include <hip/hip_runtime.h>
#include <hip/hip_bf16.h>
#include <stdint.h>

using f32x4 = __attribute__((ext_vector_type(4))) float;
using s16x8 = __attribute__((ext_vector_type(8))) short;
using s16x4 = __attribute__((ext_vector_type(4))) short;

__device__ __forceinline__ unsigned short f2bf(float f) {
  union { float f; unsigned int u; } v; v.f = f;
  return (unsigned short)((v.u + 0x7FFFu + ((v.u >> 16) & 1u)) >> 16);
}

__device__ __forceinline__ float exp2_(float x) {
  float r;
  asm("v_exp_f32 %0, %1" : "=v"(r) : "v"(x));
  return r;
}

// pack 2 f32 -> u32 of 2 bf16 (lo=a, hi=b) via single v_cvt_pk_bf16_f32
__device__ __forceinline__ unsigned cvtpk(float a, float b) {
  unsigned r;
  asm("v_cvt_pk_bf16_f32 %0, %1, %2" : "=v"(r) : "v"(a), "v"(b));
  return r;
}

__device__ __forceinline__ short pbf(float f) {
  __hip_bfloat16 h = __float2bfloat16(f);
  return *(short*)&h;
}

#define GLD16(gp, lp) __builtin_amdgcn_global_load_lds( \
    (const __attribute__((address_space(1))) unsigned int*)(uintptr_t)(gp), \
    (__attribute__((address_space(3))) unsigned int*)(uintptr_t)(lp), 16, 0, 0)

__device__ __forceinline__ f32x4 mfma32(s16x8 a, s16x8 b, f32x4 c) {
  return __builtin_amdgcn_mfma_f32_16x16x32_bf16(a, b, c, 0, 0, 0);
}

// ---------------- prep: fused x-convert + 4 weight transposes ----------------
__global__ __launch_bounds__(256)
void prep(const float* __restrict__ x,
          const float* __restrict__ Wq, const float* __restrict__ Wk,
          const float* __restrict__ Wv, const float* __restrict__ Wo,
          unsigned short* __restrict__ xb, unsigned short* __restrict__ Wt) {
  __shared__ float tile[64][65];
  int blk = blockIdx.x;
  int tid = threadIdx.x;
  if (blk < 1024) {
    const float4* xi = (const float4*)x;
    ushort4* xo = (ushort4*)xb;
    #pragma unroll
    for (int j = 0; j < 4; ++j) {
      int i = blk * 1024 + j * 256 + tid;
      float4 v = xi[i];
      ushort4 o;
      o.x = f2bf(v.x); o.y = f2bf(v.y); o.z = f2bf(v.z); o.w = f2bf(v.w);
      xo[i] = o;
    }
  } else {
    int wid = blk - 1024;
    int which = wid >> 8, t = wid & 255;
    const float* W = (which == 0) ? Wq : (which == 1) ? Wk : (which == 2) ? Wv : Wo;
    unsigned short* dst = Wt + (size_t)which * 1048576;
    int k0 = (t & 15) * 64, n0 = (t >> 4) * 64;
    int tx = tid & 63, ty = tid >> 6;
    #pragma unroll
    for (int j = 0; j < 64; j += 4)
      tile[ty + j][tx] = W[(size_t)(k0 + ty + j) * 1024 + n0 + tx];
    __syncthreads();
    #pragma unroll
    for (int j = 0; j < 64; j += 4)
      dst[(size_t)(n0 + ty + j) * 1024 + k0 + tx] = f2bf(tile[tx][ty + j]);
  }
}

// ---------------- fused QKV GEMM: 256x192 tile, 8 waves, BK=64 ---------------
// Epilogue writes q (pre-scaled by log2e/8), K in K=32 A-fragment order, and
// V in K=32 B-fragment order for attention's mfma_16x16x32 PV:
//   vf[pair][ch=kv>>5][dt=dh>>4][lane=((kv>>3)&3)*16+(dh&15)][j=kv&7]
__global__ __launch_bounds__(512, 2)
void qkv_gemm(const unsigned short* __restrict__ A,
              const unsigned short* __restrict__ Bt,
              const float* __restrict__ bq, const float* __restrict__ bk,
              const float* __restrict__ bv,
              unsigned short* __restrict__ qo, unsigned short* __restrict__ kf,
              unsigned short* __restrict__ vf) {
  __shared__ unsigned short lds2[2][28672];   // per buf: A 0..16383, B 16384..28671
  int orig = blockIdx.x;                      // 256 wgs
  int wg = (orig & 7) * 32 + (orig >> 3);
  int bm = wg >> 4, bn = wg & 15;
  int m0 = bm << 8;
  int n0 = bn * 192;
  int tid = threadIdx.x;
  int w = tid >> 6, ln = tid & 63;
  int g = ln >> 4, c = ln & 15;
  int wm = w >> 2, wn = w & 3;                // 2M x 4N waves; wave = 128x48

  int rrs = tid >> 3;
  int lcol = (((tid & 7) ^ ((tid >> 3) & 7)) << 4);
  const char* pA = (const char*)A + (size_t)(m0 + rrs) * 2048 + lcol;
  const char* pB = (const char*)Bt + (size_t)(n0 + rrs) * 2048 + lcol;
  int woff = w * 1024;

#define QKV_STAGE(buf, kt)                                                     \
  {                                                                            \
    char* db = (char*)&lds2[buf][0];                                           \
    _Pragma("unroll")                                                          \
    for (int s = 0; s < 4; ++s)                                                \
      GLD16(pA + (size_t)s * 131072 + (kt) * 128, db + s * 8192 + woff);       \
    _Pragma("unroll")                                                          \
    for (int s = 0; s < 3; ++s)                                                \
      GLD16(pB + (size_t)s * 131072 + (kt) * 128,                              \
            db + 32768 + s * 8192 + woff);                                     \
  }

  int cs = (c & 7) << 4;
#define DSFA(LA, mi, kk)                                                       \
  (*(const s16x8*)&(LA)[((mi) >> 2) * 4096 + (((mi) & 3) * 16 + c) * 64 +      \
                        ((((kk) * 64 + g * 16) ^ cs) >> 1)])
#define DSFB(LB, ni, kk)                                                       \
  (*(const s16x8*)&(LB)[((wn * 48 + (ni) * 16) >> 6) * 4096 +                  \
                        (((wn * 48 + (ni) * 16) & 63) + c) * 64 +              \
                        ((((kk) * 64 + g * 16) ^ cs) >> 1)])

  f32x4 acc[8][3];
  f32x4 zero = {0.f, 0.f, 0.f, 0.f};
  #pragma unroll
  for (int mi = 0; mi < 8; ++mi)
    #pragma unroll
    for (int ni = 0; ni < 3; ++ni) acc[mi][ni] = zero;

  QKV_STAGE(0, 0);
  asm volatile("s_waitcnt vmcnt(0)" ::: "memory");
  __builtin_amdgcn_s_barrier();

  for (int kt = 0; kt < 16; ++kt) {
    int bsel = kt & 1;
    const unsigned short* LA = &lds2[bsel][wm * 8192];
    const unsigned short* LB = &lds2[bsel][16384];
    if (kt < 15) QKV_STAGE(bsel ^ 1, kt + 1);

    s16x8 bfr[3][2];
    #pragma unroll
    for (int ni = 0; ni < 3; ++ni) {
      bfr[ni][0] = DSFB(LB, ni, 0);
      bfr[ni][1] = DSFB(LB, ni, 1);
    }
    s16x8 a[4][2];
    #pragma unroll
    for (int mi = 0; mi < 4; ++mi) {
      a[mi][0] = DSFA(LA, mi, 0);
      a[mi][1] = DSFA(LA, mi, 1);
    }
    __builtin_amdgcn_s_setprio(1);
    #pragma unroll
    for (int mi = 0; mi < 4; ++mi)
      #pragma unroll
      for (int ni = 0; ni < 3; ++ni) {
        acc[mi][ni] = mfma32(a[mi][0], bfr[ni][0], acc[mi][ni]);
        acc[mi][ni] = mfma32(a[mi][1], bfr[ni][1], acc[mi][ni]);
      }
    __builtin_amdgcn_s_setprio(0);
    #pragma unroll
    for (int mi = 0; mi < 4; ++mi) {
      a[mi][0] = DSFA(LA, mi + 4, 0);
      a[mi][1] = DSFA(LA, mi + 4, 1);
    }
    __builtin_amdgcn_s_setprio(1);
    #pragma unroll
    for (int mi = 0; mi < 4; ++mi)
      #pragma unroll
      for (int ni = 0; ni < 3; ++ni) {
        acc[mi + 4][ni] = mfma32(a[mi][0], bfr[ni][0], acc[mi + 4][ni]);
        acc[mi + 4][ni] = mfma32(a[mi][1], bfr[ni][1], acc[mi + 4][ni]);
      }
    __builtin_amdgcn_s_setprio(0);

    asm volatile("s_waitcnt vmcnt(0)" ::: "memory");
    __builtin_amdgcn_s_barrier();
  }
#undef QKV_STAGE
#undef DSFA
#undef DSFB

  #pragma unroll
  for (int ni = 0; ni < 3; ++ni) {
    int cg = n0 + wn * 48 + ni * 16 + c;    // 0..3071
    int p = cg >> 10;                        // 0=q 1=k 2=v
    int d = cg & 1023;
    int hh = d >> 6, dh = d & 63;
    const float* bp = (p == 0) ? bq : (p == 1) ? bk : bv;
    float bias = bp[d];
    #pragma unroll
    for (int mi = 0; mi < 8; ++mi) {
      int r = m0 + wm * 128 + mi * 16 + g * 4;  // rows r..r+3 (e=0..3)
      int b2 = r >> 11, s = r & 2047;
      size_t pv = (size_t)((b2 << 4) + hh);
      if (p == 2) {
        // V in K=32 B-fragment order: [ch][dt][lane16][j]
        int ch = s >> 5;
        int l16 = ((s >> 3) & 3) * 16 + (dh & 15);
        int jo = s & 7;
        ushort4 pk;
        pk.x = f2bf(acc[mi][ni][0] + bias);
        pk.y = f2bf(acc[mi][ni][1] + bias);
        pk.z = f2bf(acc[mi][ni][2] + bias);
        pk.w = f2bf(acc[mi][ni][3] + bias);
        *(ushort4*)&vf[pv * 131072 +
                       (size_t)((ch * 4 + (dh >> 4)) * 64 + l16) * 8 + jo] = pk;
      } else if (p == 1) {
        int T = s >> 4;
        int h2 = dh >> 5, gp = (dh >> 3) & 3, j = dh & 7;
        unsigned short* kd = kf + pv * 131072 + T * 1024 + h2 * 512 +
                             (gp * 16 + (s & 15)) * 8 + j;
        kd[0]  = f2bf(acc[mi][ni][0] + bias);
        kd[8]  = f2bf(acc[mi][ni][1] + bias);
        kd[16] = f2bf(acc[mi][ni][2] + bias);
        kd[24] = f2bf(acc[mi][ni][3] + bias);
      } else {
        const float sc = 0.180336880111120f;  // 1/8 * log2(e)
        size_t base = (pv * 2048 + s) * 64 + dh;
        qo[base]       = f2bf((acc[mi][ni][0] + bias) * sc);
        qo[base + 64]  = f2bf((acc[mi][ni][1] + bias) * sc);
        qo[base + 128] = f2bf((acc[mi][ni][2] + bias) * sc);
        qo[base + 192] = f2bf((acc[mi][ni][3] + bias) * sc);
      }
    }
  }
}

// ---------------- flash attention (2q x 2kv wave split, 4 waves/SIMD) --------
// R12 plateaued at ~48us across structural variants: 2 waves/SIMD barrier-
// locked => latency-bound (removing MFMA work didn't shrink the window).
// Fix: fixed-max softmax is ADDITIVE over kv (O = sum O_w, l = sum l_w), so
// split each 64-q block's 4 waves as 2 q-halves x 2 kv-halves: wave = 32q x
// 32kv slice per tile -> 1024 blocks x 4 waves = 4096 waves = 4/SIMD (2x TLP)
// at unchanged aggregate LDS traffic. Simple dbuf (32KB) + P scratch (8KB) =
// 40KB -> 4 blocks/CU. All fragment algebra identical to R12 with j/m halved.
// End: wkv=1 waves publish partial acc/l via LDS (dead KV buffers), wkv=0
// combine + store.
__global__ __launch_bounds__(256, 4)
void attn_fwd(const unsigned short* __restrict__ q,
              const unsigned short* __restrict__ kfb,
              const unsigned short* __restrict__ vfb,
              unsigned short* __restrict__ ao) {
  __shared__ unsigned short ldsKV[2][8192];  // dbuf: per buf K 0..4095, V 4096..8191
  __shared__ unsigned short ldsP[4][1024];   // per-wave P scratch (2KB)
  int orig = blockIdx.x;                    // 1024 wgs
  int wg = (orig & 7) * 128 + (orig >> 3);  // XCD-contiguous
  int pair = wg >> 5, qt = wg & 31;         // 32 blocks (64 q-rows) per pair
  int tid = threadIdx.x;
  int w = tid >> 6, ln = tid & 63;
  int g = ln >> 4, c = ln & 15;
  int wq = w >> 1, wkv = w & 1;
  int qw = qt * 64 + wq * 32;
  const unsigned short* qp = q + (size_t)pair * 131072;
  const char* kbase = (const char*)(kfb + (size_t)pair * 131072);
  const char* vbase = (const char*)(vfb + (size_t)pair * 131072);

  // staging: waves 0,1 -> K halves, waves 2,3 -> V halves; 4KB each
  const char* ssrc = ((w < 2) ? kbase : vbase) + (w & 1) * 4096;
  int dsto = (w >= 2 ? 8192 : 0) + (w & 1) * 4096;

  unsigned short* Pw = &ldsP[w][0];

  s16x8 qf[2][2];
  #pragma unroll
  for (int j = 0; j < 2; ++j)
    #pragma unroll
    for (int h = 0; h < 2; ++h)
      qf[j][h] = *(const s16x8*)&qp[(qw + j * 16 + c) * 64 + h * 32 + g * 8];

  f32x4 acc[2][4];
  f32x4 zero = {0.f, 0.f, 0.f, 0.f};
  #pragma unroll
  for (int j = 0; j < 2; ++j)
    #pragma unroll
    for (int dt = 0; dt < 4; ++dt) acc[j][dt] = zero;
  float l0 = 0.f, l1 = 0.f;

  // prologue: stage tile 0 into buffer 0
  #pragma unroll
  for (int jj = 0; jj < 4; ++jj)
    GLD16(ssrc + jj * 1024 + ln * 16, (char*)&ldsKV[0][0] + dsto + jj * 1024);

  int kofs = wkv * 2048;   // my K slice: kt-tiles {2wkv, 2wkv+1}

  for (int t = 0; t < 32; ++t) {
    int buf = t & 1;
    if (t < 31) {
      const char* s2 = ssrc + (size_t)(t + 1) * 8192;
      char* d2 = (char*)&ldsKV[buf ^ 1][0] + dsto;
      #pragma unroll
      for (int jj = 0; jj < 4; ++jj)
        GLD16(s2 + jj * 1024 + ln * 16, d2 + jj * 1024);
      asm volatile("s_waitcnt vmcnt(4)" ::: "memory");
    } else {
      asm volatile("s_waitcnt vmcnt(0)" ::: "memory");
    }
    __builtin_amdgcn_s_barrier();

    const unsigned short* L = ldsKV[buf];
    // K slice fragments (stride-1 b128)
    s16x8 kc[2][2];
    #pragma unroll
    for (int ktl = 0; ktl < 2; ++ktl) {
      kc[ktl][0] = *(const s16x8*)&L[kofs + ktl * 1024 + ln * 8];
      kc[ktl][1] = *(const s16x8*)&L[kofs + ktl * 1024 + 512 + ln * 8];
    }
    // QK^T: S^T[32kv-slice x 32q]
    f32x4 st[2][2];
    __builtin_amdgcn_s_setprio(1);
    #pragma unroll
    for (int ktl = 0; ktl < 2; ++ktl)
      #pragma unroll
      for (int j = 0; j < 2; ++j) {
        f32x4 t2 = zero;
        t2 = mfma32(kc[ktl][0], qf[j][0], t2);
        t2 = mfma32(kc[ktl][1], qf[j][1], t2);
        st[ktl][j] = t2;
      }
    __builtin_amdgcn_s_setprio(0);

    // V slice (K=32 B-frag chunk m = wkv)
    s16x8 vv[4];
    #pragma unroll
    for (int dt = 0; dt < 4; ++dt)
      vv[dt] = *(const s16x8*)&L[4096 + wkv * 2048 + dt * 512 + ln * 8];

    // P = exp2(S), pack to K=32 A-frag layout in private LDS, l partials
    #pragma unroll
    for (int ktl = 0; ktl < 2; ++ktl)
      #pragma unroll
      for (int j = 0; j < 2; ++j) {
        float p0 = exp2_(st[ktl][j][0]), p1 = exp2_(st[ktl][j][1]);
        float p2 = exp2_(st[ktl][j][2]), p3 = exp2_(st[ktl][j][3]);
        if (j == 0) l0 += (p0 + p1) + (p2 + p3);
        else        l1 += (p0 + p1) + (p2 + p3);
        int wa = j * 512 + (2 * ktl + (g >> 1)) * 128 + c * 8 + (g & 1) * 4;
        uint2 ww;
        ww.x = cvtpk(p0, p1);
        ww.y = cvtpk(p2, p3);
        *(uint2*)&Pw[wa] = ww;
      }
    // P read back as A-fragments (wave-in-order DS => no barrier needed)
    s16x8 pa0 = *(const s16x8*)&Pw[ln * 8];
    s16x8 pa1 = *(const s16x8*)&Pw[512 + ln * 8];

    // PV: acc += P * V (K=32 rate)
    __builtin_amdgcn_s_setprio(1);
    #pragma unroll
    for (int dt = 0; dt < 4; ++dt) {
      acc[0][dt] = mfma32(pa0, vv[dt], acc[0][dt]);
      acc[1][dt] = mfma32(pa1, vv[dt], acc[1][dt]);
    }
    __builtin_amdgcn_s_setprio(0);

    __builtin_amdgcn_s_barrier();
  }

  // ---- cross-wave kv combine (fixed-max softmax => purely additive) ----
  float* red = (float*)&ldsKV[0][0];       // KV buffers dead; 17.4KB used
  float* r = red + wq * 2176;
  if (wkv == 1) {
    #pragma unroll
    for (int j = 0; j < 2; ++j)
      #pragma unroll
      for (int dt = 0; dt < 4; ++dt)
        *(f32x4*)&r[(j * 4 + dt) * 256 + ln * 4] = acc[j][dt];
    r[2048 + ln] = l0;
    r[2048 + 64 + ln] = l1;
  }
  __syncthreads();
  if (wkv == 0) {
    #pragma unroll
    for (int j = 0; j < 2; ++j)
      #pragma unroll
      for (int dt = 0; dt < 4; ++dt)
        acc[j][dt] += *(const f32x4*)&r[(j * 4 + dt) * 256 + ln * 4];
    l0 += r[2048 + ln];
    l1 += r[2048 + 64 + ln];
    // reduce l over the 4 g-copies of each q-column
    l0 += __shfl_xor(l0, 16); l0 += __shfl_xor(l0, 32);
    l1 += __shfl_xor(l1, 16); l1 += __shfl_xor(l1, 32);
    float li0 = 1.f / l0, li1 = 1.f / l1;
    int b = pair >> 4, hh = pair & 15;
    #pragma unroll
    for (int e = 0; e < 4; ++e) {
      float i0 = __shfl(li0, g * 4 + e);
      float i1 = __shfl(li1, g * 4 + e);
      size_t r0 = ((size_t)(b * 2048 + qw + g * 4 + e) * 16 + hh) * 64;
      size_t r1 = ((size_t)(b * 2048 + qw + 16 + g * 4 + e) * 16 + hh) * 64;
      #pragma unroll
      for (int dt = 0; dt < 4; ++dt) {
        ao[r0 + dt * 16 + c] = (unsigned short)pbf(acc[0][dt][e] * i0);
        ao[r1 + dt * 16 + c] = (unsigned short)pbf(acc[1][dt][e] * i1);
      }
    }
  }
}

// ---------------- output GEMM: ao[4096,1024] x Wo -> fp32 out ----------------
__global__ __launch_bounds__(256)
void out_gemm(const unsigned short* __restrict__ A,
              const unsigned short* __restrict__ Bt,
              const float* __restrict__ bo, float* __restrict__ out) {
  __shared__ unsigned short lds[2][6144];   // A @0..2047, B @2048..6143
  int orig = blockIdx.x;                    // 512 wgs
  int wg = (orig & 7) * 64 + (orig >> 3);
  int bm = wg >> 3, bn = wg & 7;
  int m0 = bm << 6, n0 = bn << 7;
  int tid = threadIdx.x;
  int w = tid >> 6, ln = tid & 63;
  int g = ln >> 4, c = ln & 15;
  int wr = w >> 1, wc = w & 1;

  const unsigned short* su[3];
  int du[3];
  #pragma unroll
  for (int i = 0; i < 3; ++i) {
    int u = 3 * w + i;
    if (u < 4) {
      su[i] = A + (size_t)(m0 + u * 16 + (ln >> 2)) * 1024 + (ln & 3) * 8;
      du[i] = u * 512;
    } else {
      int v2 = u - 4;
      su[i] = Bt + (size_t)(n0 + v2 * 16 + (ln >> 2)) * 1024 + (ln & 3) * 8;
      du[i] = 2048 + v2 * 512;
    }
  }

  f32x4 acc[2][4];
  f32x4 zero = {0.f, 0.f, 0.f, 0.f};
  #pragma unroll
  for (int m = 0; m < 2; ++m)
    #pragma unroll
    for (int n = 0; n < 4; ++n) acc[m][n] = zero;

  #pragma unroll
  for (int i = 0; i < 3; ++i) GLD16(su[i], &lds[0][du[i]]);
  __syncthreads();

  int aoff = (wr * 32 + c) * 32 + g * 8;
  int boff = 2048 + (wc * 64 + c) * 32 + g * 8;

  int cur = 0;
  for (int t = 0; t < 32; ++t) {
    if (t < 31) {
      int nb = cur ^ 1;
      #pragma unroll
      for (int i = 0; i < 3; ++i) GLD16(su[i] + (t + 1) * 32, &lds[nb][du[i]]);
    }
    s16x8 af[2], bf[4];
    #pragma unroll
    for (int m = 0; m < 2; ++m)
      af[m] = *(const s16x8*)&lds[cur][aoff + m * 512];
    #pragma unroll
    for (int n = 0; n < 4; ++n)
      bf[n] = *(const s16x8*)&lds[cur][boff + n * 512];
    #pragma unroll
    for (int m = 0; m < 2; ++m)
      #pragma unroll
      for (int n = 0; n < 4; ++n)
        acc[m][n] = mfma32(af[m], bf[n], acc[m][n]);
    __syncthreads();
    cur ^= 1;
  }

  #pragma unroll
  for (int n = 0; n < 4; ++n) {
    int cg = n0 + wc * 64 + n * 16 + c;
    float bias = bo[cg];
    #pragma unroll
    for (int m = 0; m < 2; ++m) {
      int r = m0 + wr * 32 + m * 16 + g * 4;
      out[(size_t)r * 1024 + cg] = acc[m][n][0] + bias;
      out[(size_t)(r + 1) * 1024 + cg] = acc[m][n][1] + bias;
      out[(size_t)(r + 2) * 1024 + cg] = acc[m][n][2] + bias;
      out[(size_t)(r + 3) * 1024 + cg] = acc[m][n][3] + bias;
    }
  }
}

extern "C" void kernel_launch(void* const* d_in, const int* in_sizes, int n_in,
                              void* d_out, int out_size, void* d_ws, size_t ws_size,
                              hipStream_t stream) {
  (void)in_sizes; (void)n_in; (void)out_size; (void)ws_size;
  const float* x  = (const float*)d_in[0];
  const float* Wq = (const float*)d_in[1];
  const float* bq = (const float*)d_in[2];
  const float* Wk = (const float*)d_in[3];
  const float* bk = (const float*)d_in[4];
  const float* Wv = (const float*)d_in[5];
  const float* bv = (const float*)d_in[6];
  const float* Wo = (const float*)d_in[7];
  const float* bo = (const float*)d_in[8];
  float* out = (float*)d_out;
  char* ws = (char*)d_ws;
  unsigned short* xb  = (unsigned short*)(ws);             // [4096][1024] bf16
  unsigned short* Wt  = (unsigned short*)(ws + 8388608);   // [Wq^T|Wk^T|Wv^T|Wo^T]
  unsigned short* Wot = (unsigned short*)(ws + 14680064);  // = Wt + 3*1048576
  unsigned short* qb  = (unsigned short*)(ws + 16777216);  // pre-scaled q
  unsigned short* kfb = (unsigned short*)(ws + 25165824);  // K fragment-order
  unsigned short* vfb = (unsigned short*)(ws + 33554432);  // V K=32 B-fragment order
  unsigned short* ao  = (unsigned short*)(ws + 41943040);  // [B,S,H,Dh] bf16

  prep<<<2048, 256, 0, stream>>>(x, Wq, Wk, Wv, Wo, xb, Wt);
  qkv_gemm<<<256, 512, 0, stream>>>(xb, Wt, bq, bk, bv, qb, kfb, vfb);
  attn_fwd<<<1024, 256, 0, stream>>>(qb, kfb, vfb, ao);
  out_gemm<<<512, 256, 0, stream>>>(ao, Wot, bo, out);
}

// Round 14
// 101.009 us; speedup vs baseline: 1.0447x; 1.0447x over previous
//
#include <hip/hip_runtime.h>
#include <hip/hip_bf16.h>
#include <stdint.h>

using f32x4 = __attribute__((ext_vector_type(4))) float;
using s16x8 = __attribute__((ext_vector_type(8))) short;
using s16x4 = __attribute__((ext_vector_type(4))) short;

__device__ __forceinline__ unsigned short f2bf(float f) {
  union { float f; unsigned int u; } v; v.f = f;
  return (unsigned short)((v.u + 0x7FFFu + ((v.u >> 16) & 1u)) >> 16);
}

__device__ __forceinline__ float exp2_(float x) {
  float r;
  asm("v_exp_f32 %0, %1" : "=v"(r) : "v"(x));
  return r;
}

// pack 2 f32 -> u32 of 2 bf16 (lo=a, hi=b) via single v_cvt_pk_bf16_f32
__device__ __forceinline__ unsigned cvtpk(float a, float b) {
  unsigned r;
  asm("v_cvt_pk_bf16_f32 %0, %1, %2" : "=v"(r) : "v"(a), "v"(b));
  return r;
}

__device__ __forceinline__ short pbf(float f) {
  __hip_bfloat16 h = __float2bfloat16(f);
  return *(short*)&h;
}

#define GLD16(gp, lp) __builtin_amdgcn_global_load_lds( \
    (const __attribute__((address_space(1))) unsigned int*)(uintptr_t)(gp), \
    (__attribute__((address_space(3))) unsigned int*)(uintptr_t)(lp), 16, 0, 0)

__device__ __forceinline__ f32x4 mfma32(s16x8 a, s16x8 b, f32x4 c) {
  return __builtin_amdgcn_mfma_f32_16x16x32_bf16(a, b, c, 0, 0, 0);
}

// ---------------- prep: fused x-convert + 4 weight transposes ----------------
__global__ __launch_bounds__(256)
void prep(const float* __restrict__ x,
          const float* __restrict__ Wq, const float* __restrict__ Wk,
          const float* __restrict__ Wv, const float* __restrict__ Wo,
          unsigned short* __restrict__ xb, unsigned short* __restrict__ Wt) {
  __shared__ float tile[64][65];
  int blk = blockIdx.x;
  int tid = threadIdx.x;
  if (blk < 1024) {
    const float4* xi = (const float4*)x;
    ushort4* xo = (ushort4*)xb;
    #pragma unroll
    for (int j = 0; j < 4; ++j) {
      int i = blk * 1024 + j * 256 + tid;
      float4 v = xi[i];
      ushort4 o;
      o.x = f2bf(v.x); o.y = f2bf(v.y); o.z = f2bf(v.z); o.w = f2bf(v.w);
      xo[i] = o;
    }
  } else {
    int wid = blk - 1024;
    int which = wid >> 8, t = wid & 255;
    const float* W = (which == 0) ? Wq : (which == 1) ? Wk : (which == 2) ? Wv : Wo;
    unsigned short* dst = Wt + (size_t)which * 1048576;
    int k0 = (t & 15) * 64, n0 = (t >> 4) * 64;
    int tx = tid & 63, ty = tid >> 6;
    #pragma unroll
    for (int j = 0; j < 64; j += 4)
      tile[ty + j][tx] = W[(size_t)(k0 + ty + j) * 1024 + n0 + tx];
    __syncthreads();
    #pragma unroll
    for (int j = 0; j < 64; j += 4)
      dst[(size_t)(n0 + ty + j) * 1024 + k0 + tx] = f2bf(tile[tx][ty + j]);
  }
}

// ---------------- fused QKV GEMM: 256x192 tile, 8 waves, BK=64 ---------------
// Epilogue writes q (pre-scaled by log2e/8), K in K=32 A-fragment order, and
// V in K=32 B-fragment order for attention's mfma_16x16x32 PV:
//   vf[pair][ch=kv>>5][dt=dh>>4][lane=((kv>>3)&3)*16+(dh&15)][j=kv&7]
__global__ __launch_bounds__(512, 2)
void qkv_gemm(const unsigned short* __restrict__ A,
              const unsigned short* __restrict__ Bt,
              const float* __restrict__ bq, const float* __restrict__ bk,
              const float* __restrict__ bv,
              unsigned short* __restrict__ qo, unsigned short* __restrict__ kf,
              unsigned short* __restrict__ vf) {
  __shared__ unsigned short lds2[2][28672];   // per buf: A 0..16383, B 16384..28671
  int orig = blockIdx.x;                      // 256 wgs
  int wg = (orig & 7) * 32 + (orig >> 3);
  int bm = wg >> 4, bn = wg & 15;
  int m0 = bm << 8;
  int n0 = bn * 192;
  int tid = threadIdx.x;
  int w = tid >> 6, ln = tid & 63;
  int g = ln >> 4, c = ln & 15;
  int wm = w >> 2, wn = w & 3;                // 2M x 4N waves; wave = 128x48

  int rrs = tid >> 3;
  int lcol = (((tid & 7) ^ ((tid >> 3) & 7)) << 4);
  const char* pA = (const char*)A + (size_t)(m0 + rrs) * 2048 + lcol;
  const char* pB = (const char*)Bt + (size_t)(n0 + rrs) * 2048 + lcol;
  int woff = w * 1024;

#define QKV_STAGE(buf, kt)                                                     \
  {                                                                            \
    char* db = (char*)&lds2[buf][0];                                           \
    _Pragma("unroll")                                                          \
    for (int s = 0; s < 4; ++s)                                                \
      GLD16(pA + (size_t)s * 131072 + (kt) * 128, db + s * 8192 + woff);       \
    _Pragma("unroll")                                                          \
    for (int s = 0; s < 3; ++s)                                                \
      GLD16(pB + (size_t)s * 131072 + (kt) * 128,                              \
            db + 32768 + s * 8192 + woff);                                     \
  }

  int cs = (c & 7) << 4;
#define DSFA(LA, mi, kk)                                                       \
  (*(const s16x8*)&(LA)[((mi) >> 2) * 4096 + (((mi) & 3) * 16 + c) * 64 +      \
                        ((((kk) * 64 + g * 16) ^ cs) >> 1)])
#define DSFB(LB, ni, kk)                                                       \
  (*(const s16x8*)&(LB)[((wn * 48 + (ni) * 16) >> 6) * 4096 +                  \
                        (((wn * 48 + (ni) * 16) & 63) + c) * 64 +              \
                        ((((kk) * 64 + g * 16) ^ cs) >> 1)])

  f32x4 acc[8][3];
  f32x4 zero = {0.f, 0.f, 0.f, 0.f};
  #pragma unroll
  for (int mi = 0; mi < 8; ++mi)
    #pragma unroll
    for (int ni = 0; ni < 3; ++ni) acc[mi][ni] = zero;

  QKV_STAGE(0, 0);
  asm volatile("s_waitcnt vmcnt(0)" ::: "memory");
  __builtin_amdgcn_s_barrier();

  for (int kt = 0; kt < 16; ++kt) {
    int bsel = kt & 1;
    const unsigned short* LA = &lds2[bsel][wm * 8192];
    const unsigned short* LB = &lds2[bsel][16384];
    if (kt < 15) QKV_STAGE(bsel ^ 1, kt + 1);

    s16x8 bfr[3][2];
    #pragma unroll
    for (int ni = 0; ni < 3; ++ni) {
      bfr[ni][0] = DSFB(LB, ni, 0);
      bfr[ni][1] = DSFB(LB, ni, 1);
    }
    s16x8 a[4][2];
    #pragma unroll
    for (int mi = 0; mi < 4; ++mi) {
      a[mi][0] = DSFA(LA, mi, 0);
      a[mi][1] = DSFA(LA, mi, 1);
    }
    __builtin_amdgcn_s_setprio(1);
    #pragma unroll
    for (int mi = 0; mi < 4; ++mi)
      #pragma unroll
      for (int ni = 0; ni < 3; ++ni) {
        acc[mi][ni] = mfma32(a[mi][0], bfr[ni][0], acc[mi][ni]);
        acc[mi][ni] = mfma32(a[mi][1], bfr[ni][1], acc[mi][ni]);
      }
    __builtin_amdgcn_s_setprio(0);
    #pragma unroll
    for (int mi = 0; mi < 4; ++mi) {
      a[mi][0] = DSFA(LA, mi + 4, 0);
      a[mi][1] = DSFA(LA, mi + 4, 1);
    }
    __builtin_amdgcn_s_setprio(1);
    #pragma unroll
    for (int mi = 0; mi < 4; ++mi)
      #pragma unroll
      for (int ni = 0; ni < 3; ++ni) {
        acc[mi + 4][ni] = mfma32(a[mi][0], bfr[ni][0], acc[mi + 4][ni]);
        acc[mi + 4][ni] = mfma32(a[mi][1], bfr[ni][1], acc[mi + 4][ni]);
      }
    __builtin_amdgcn_s_setprio(0);

    asm volatile("s_waitcnt vmcnt(0)" ::: "memory");
    __builtin_amdgcn_s_barrier();
  }
#undef QKV_STAGE
#undef DSFA
#undef DSFB

  #pragma unroll
  for (int ni = 0; ni < 3; ++ni) {
    int cg = n0 + wn * 48 + ni * 16 + c;    // 0..3071
    int p = cg >> 10;                        // 0=q 1=k 2=v
    int d = cg & 1023;
    int hh = d >> 6, dh = d & 63;
    const float* bp = (p == 0) ? bq : (p == 1) ? bk : bv;
    float bias = bp[d];
    #pragma unroll
    for (int mi = 0; mi < 8; ++mi) {
      int r = m0 + wm * 128 + mi * 16 + g * 4;  // rows r..r+3 (e=0..3)
      int b2 = r >> 11, s = r & 2047;
      size_t pv = (size_t)((b2 << 4) + hh);
      if (p == 2) {
        // V in K=32 B-fragment order: [ch][dt][lane16][j]
        int ch = s >> 5;
        int l16 = ((s >> 3) & 3) * 16 + (dh & 15);
        int jo = s & 7;
        ushort4 pk;
        pk.x = f2bf(acc[mi][ni][0] + bias);
        pk.y = f2bf(acc[mi][ni][1] + bias);
        pk.z = f2bf(acc[mi][ni][2] + bias);
        pk.w = f2bf(acc[mi][ni][3] + bias);
        *(ushort4*)&vf[pv * 131072 +
                       (size_t)((ch * 4 + (dh >> 4)) * 64 + l16) * 8 + jo] = pk;
      } else if (p == 1) {
        int T = s >> 4;
        int h2 = dh >> 5, gp = (dh >> 3) & 3, j = dh & 7;
        unsigned short* kd = kf + pv * 131072 + T * 1024 + h2 * 512 +
                             (gp * 16 + (s & 15)) * 8 + j;
        kd[0]  = f2bf(acc[mi][ni][0] + bias);
        kd[8]  = f2bf(acc[mi][ni][1] + bias);
        kd[16] = f2bf(acc[mi][ni][2] + bias);
        kd[24] = f2bf(acc[mi][ni][3] + bias);
      } else {
        const float sc = 0.180336880111120f;  // 1/8 * log2(e)
        size_t base = (pv * 2048 + s) * 64 + dh;
        qo[base]       = f2bf((acc[mi][ni][0] + bias) * sc);
        qo[base + 64]  = f2bf((acc[mi][ni][1] + bias) * sc);
        qo[base + 128] = f2bf((acc[mi][ni][2] + bias) * sc);
        qo[base + 192] = f2bf((acc[mi][ni][3] + bias) * sc);
      }
    }
  }
}

// ---------------- flash attention (quad-buffer ring, ONE barrier/iter) -------
// Diagnosis from R6/R8/R12/R13: per-iter window ~3600cyc is invariant under
// work content, pipe mix, and TLP -> the wall is per-iteration sync overhead
// (2 barriers + vmcnt per iter). Fix: 4-deep LDS buffer ring removes the
// trailing barrier. At iter t: stage -> (t+1)&3, compute K/V from (t)&3, PV's
// V from (t-1)&3. Max skew under ONE barrier: fast wave stages (t+2)&3 while
// slow wave reads (t)&3 / (t-1)&3 -- all distinct mod 4 => race-free.
// Everything else identical to R12 (K=32 PV, private-LDS P transport, counted
// vmcnt(4), 32q/wave). LDS 64KB KV + 16KB P = 80KB -> 2 blocks/CU.
__global__ __launch_bounds__(256, 2)
void attn_fwd(const unsigned short* __restrict__ q,
              const unsigned short* __restrict__ kfb,
              const unsigned short* __restrict__ vfb,
              unsigned short* __restrict__ ao) {
  __shared__ unsigned short ldsKV[4][8192];  // ring: per buf K 0..4095, V 4096..8191
  __shared__ unsigned short ldsP[4][2048];   // wave-private P scratch (4KB/wave)
  int orig = blockIdx.x;                    // 512 wgs
  int wg = (orig & 7) * 64 + (orig >> 3);   // XCD-contiguous
  int pair = wg >> 4, qt = wg & 15;
  int tid = threadIdx.x;
  int w = tid >> 6, ln = tid & 63;
  int g = ln >> 4, c = ln & 15;
  int q0 = qt * 128 + w * 32;
  const unsigned short* qp = q + (size_t)pair * 131072;
  const char* kbase = (const char*)(kfb + (size_t)pair * 131072);
  const char* vbase = (const char*)(vfb + (size_t)pair * 131072);

  const char* ssrc = ((w < 2) ? kbase : vbase) + (w & 1) * 4096;
  int dsto = (w >= 2 ? 8192 : 0) + (w & 1) * 4096;

  unsigned short* Pw = &ldsP[w][0];
  int pwbase = (g >> 1) * 128 + c * 8 + (g & 1) * 4;

  s16x8 qf[2][2];
  #pragma unroll
  for (int j = 0; j < 2; ++j)
    #pragma unroll
    for (int h = 0; h < 2; ++h)
      qf[j][h] = *(const s16x8*)&qp[(q0 + j * 16 + c) * 64 + h * 32 + g * 8];

  f32x4 acc[2][4];
  f32x4 zero = {0.f, 0.f, 0.f, 0.f};
  #pragma unroll
  for (int j = 0; j < 2; ++j)
    #pragma unroll
    for (int dt = 0; dt < 4; ++dt) acc[j][dt] = zero;
  float l0 = 0.f, l1 = 0.f;

  // prologue: stage tile 0 into ring slot 0
  #pragma unroll
  for (int jj = 0; jj < 4; ++jj)
    GLD16(ssrc + jj * 1024 + ln * 16, (char*)&ldsKV[0][0] + dsto + jj * 1024);

  const unsigned short* L0 = ldsKV[0];
  const unsigned short* L1 = ldsKV[1];
  const unsigned short* L2 = ldsKV[2];
  const unsigned short* L3 = ldsKV[3];

#define ATTN_ITER(T, LC, LP, LN)                                               \
  {                                                                            \
    if ((T) < 31) {                                                            \
      const char* s2 = ssrc + (size_t)((T) + 1) * 8192;                        \
      char* d2 = (char*)(LN) + dsto;                                           \
      _Pragma("unroll")                                                        \
      for (int jj = 0; jj < 4; ++jj)                                           \
        GLD16(s2 + jj * 1024 + ln * 16, d2 + jj * 1024);                       \
      asm volatile("s_waitcnt vmcnt(4)" ::: "memory");                         \
    } else {                                                                   \
      asm volatile("s_waitcnt vmcnt(0)" ::: "memory");                         \
    }                                                                          \
    __builtin_amdgcn_s_barrier();                                              \
    s16x8 kc[4][2];                                                            \
    _Pragma("unroll")                                                          \
    for (int kt = 0; kt < 4; ++kt) {                                           \
      kc[kt][0] = *(const s16x8*)&(LC)[kt * 1024 + ln * 8];                    \
      kc[kt][1] = *(const s16x8*)&(LC)[kt * 1024 + 512 + ln * 8];              \
    }                                                                          \
    f32x4 st[4][2];                                                            \
    __builtin_amdgcn_s_setprio(1);                                             \
    _Pragma("unroll")                                                          \
    for (int kt = 0; kt < 4; ++kt)                                             \
      _Pragma("unroll")                                                        \
      for (int j = 0; j < 2; ++j) {                                            \
        f32x4 t2 = zero;                                                       \
        t2 = mfma32(kc[kt][0], qf[j][0], t2);                                  \
        t2 = mfma32(kc[kt][1], qf[j][1], t2);                                  \
        st[kt][j] = t2;                                                        \
      }                                                                        \
    __builtin_amdgcn_s_setprio(0);                                             \
    if ((T) > 0) {                                                             \
      s16x8 pa00 = *(const s16x8*)&Pw[ln * 8];                                 \
      s16x8 pa01 = *(const s16x8*)&Pw[512 + ln * 8];                           \
      s16x8 pa10 = *(const s16x8*)&Pw[1024 + ln * 8];                          \
      s16x8 pa11 = *(const s16x8*)&Pw[1536 + ln * 8];                          \
      __builtin_amdgcn_s_setprio(1);                                           \
      _Pragma("unroll")                                                        \
      for (int m = 0; m < 2; ++m)                                              \
        _Pragma("unroll")                                                      \
        for (int dt = 0; dt < 4; ++dt) {                                       \
          s16x8 vv = *(const s16x8*)&(LP)[4096 + m * 2048 + dt * 512 + ln * 8];\
          acc[0][dt] = mfma32(m ? pa01 : pa00, vv, acc[0][dt]);                \
          acc[1][dt] = mfma32(m ? pa11 : pa10, vv, acc[1][dt]);                \
        }                                                                      \
      __builtin_amdgcn_s_setprio(0);                                           \
    }                                                                          \
    _Pragma("unroll")                                                          \
    for (int kt = 0; kt < 4; ++kt) {                                           \
      float p00 = exp2_(st[kt][0][0]), p01 = exp2_(st[kt][0][1]);              \
      float p02 = exp2_(st[kt][0][2]), p03 = exp2_(st[kt][0][3]);              \
      float p10 = exp2_(st[kt][1][0]), p11 = exp2_(st[kt][1][1]);              \
      float p12 = exp2_(st[kt][1][2]), p13 = exp2_(st[kt][1][3]);              \
      l0 += (p00 + p01) + (p02 + p03);                                         \
      l1 += (p10 + p11) + (p12 + p13);                                         \
      int wa = (kt >> 1) * 512 + (kt & 1) * 256 + pwbase;                      \
      uint2 w0; w0.x = cvtpk(p00, p01); w0.y = cvtpk(p02, p03);                \
      *(uint2*)&Pw[wa] = w0;                                                   \
      uint2 w1; w1.x = cvtpk(p10, p11); w1.y = cvtpk(p12, p13);                \
      *(uint2*)&Pw[1024 + wa] = w1;                                            \
    }                                                                          \
  }

  for (int t = 0; t < 32; t += 4) {
    ATTN_ITER(t,     L0, L3, L1);
    ATTN_ITER(t + 1, L1, L0, L2);
    ATTN_ITER(t + 2, L2, L1, L3);
    ATTN_ITER(t + 3, L3, L2, L0);
  }
#undef ATTN_ITER

  // final PV(31): tile 31 lives in ring slot 3; P(31) in Pw
  {
    s16x8 pa00 = *(const s16x8*)&Pw[ln * 8];
    s16x8 pa01 = *(const s16x8*)&Pw[512 + ln * 8];
    s16x8 pa10 = *(const s16x8*)&Pw[1024 + ln * 8];
    s16x8 pa11 = *(const s16x8*)&Pw[1536 + ln * 8];
    __builtin_amdgcn_s_setprio(1);
    #pragma unroll
    for (int m = 0; m < 2; ++m)
      #pragma unroll
      for (int dt = 0; dt < 4; ++dt) {
        s16x8 vv = *(const s16x8*)&L3[4096 + m * 2048 + dt * 512 + ln * 8];
        acc[0][dt] = mfma32(m ? pa01 : pa00, vv, acc[0][dt]);
        acc[1][dt] = mfma32(m ? pa11 : pa10, vv, acc[1][dt]);
      }
    __builtin_amdgcn_s_setprio(0);
  }

  // final l reduction across the 4 g-copies of each q-column
  l0 += __shfl_xor(l0, 16); l0 += __shfl_xor(l0, 32);
  l1 += __shfl_xor(l1, 16); l1 += __shfl_xor(l1, 32);
  float li0 = 1.f / l0, li1 = 1.f / l1;
  int b = pair >> 4, hh = pair & 15;
  #pragma unroll
  for (int e = 0; e < 4; ++e) {
    float i0 = __shfl(li0, g * 4 + e);
    float i1 = __shfl(li1, g * 4 + e);
    size_t r0 = ((size_t)(b * 2048 + q0 + g * 4 + e) * 16 + hh) * 64;
    size_t r1 = ((size_t)(b * 2048 + q0 + 16 + g * 4 + e) * 16 + hh) * 64;
    #pragma unroll
    for (int dt = 0; dt < 4; ++dt) {
      ao[r0 + dt * 16 + c] = (unsigned short)pbf(acc[0][dt][e] * i0);
      ao[r1 + dt * 16 + c] = (unsigned short)pbf(acc[1][dt][e] * i1);
    }
  }
}

// ---------------- output GEMM: ao[4096,1024] x Wo -> fp32 out ----------------
__global__ __launch_bounds__(256)
void out_gemm(const unsigned short* __restrict__ A,
              const unsigned short* __restrict__ Bt,
              const float* __restrict__ bo, float* __restrict__ out) {
  __shared__ unsigned short lds[2][6144];   // A @0..2047, B @2048..6143
  int orig = blockIdx.x;                    // 512 wgs
  int wg = (orig & 7) * 64 + (orig >> 3);
  int bm = wg >> 3, bn = wg & 7;
  int m0 = bm << 6, n0 = bn << 7;
  int tid = threadIdx.x;
  int w = tid >> 6, ln = tid & 63;
  int g = ln >> 4, c = ln & 15;
  int wr = w >> 1, wc = w & 1;

  const unsigned short* su[3];
  int du[3];
  #pragma unroll
  for (int i = 0; i < 3; ++i) {
    int u = 3 * w + i;
    if (u < 4) {
      su[i] = A + (size_t)(m0 + u * 16 + (ln >> 2)) * 1024 + (ln & 3) * 8;
      du[i] = u * 512;
    } else {
      int v2 = u - 4;
      su[i] = Bt + (size_t)(n0 + v2 * 16 + (ln >> 2)) * 1024 + (ln & 3) * 8;
      du[i] = 2048 + v2 * 512;
    }
  }

  f32x4 acc[2][4];
  f32x4 zero = {0.f, 0.f, 0.f, 0.f};
  #pragma unroll
  for (int m = 0; m < 2; ++m)
    #pragma unroll
    for (int n = 0; n < 4; ++n) acc[m][n] = zero;

  #pragma unroll
  for (int i = 0; i < 3; ++i) GLD16(su[i], &lds[0][du[i]]);
  __syncthreads();

  int aoff = (wr * 32 + c) * 32 + g * 8;
  int boff = 2048 + (wc * 64 + c) * 32 + g * 8;

  int cur = 0;
  for (int t = 0; t < 32; ++t) {
    if (t < 31) {
      int nb = cur ^ 1;
      #pragma unroll
      for (int i = 0; i < 3; ++i) GLD16(su[i] + (t + 1) * 32, &lds[nb][du[i]]);
    }
    s16x8 af[2], bf[4];
    #pragma unroll
    for (int m = 0; m < 2; ++m)
      af[m] = *(const s16x8*)&lds[cur][aoff + m * 512];
    #pragma unroll
    for (int n = 0; n < 4; ++n)
      bf[n] = *(const s16x8*)&lds[cur][boff + n * 512];
    #pragma unroll
    for (int m = 0; m < 2; ++m)
      #pragma unroll
      for (int n = 0; n < 4; ++n)
        acc[m][n] = mfma32(af[m], bf[n], acc[m][n]);
    __syncthreads();
    cur ^= 1;
  }

  #pragma unroll
  for (int n = 0; n < 4; ++n) {
    int cg = n0 + wc * 64 + n * 16 + c;
    float bias = bo[cg];
    #pragma unroll
    for (int m = 0; m < 2; ++m) {
      int r = m0 + wr * 32 + m * 16 + g * 4;
      out[(size_t)r * 1024 + cg] = acc[m][n][0] + bias;
      out[(size_t)(r + 1) * 1024 + cg] = acc[m][n][1] + bias;
      out[(size_t)(r + 2) * 1024 + cg] = acc[m][n][2] + bias;
      out[(size_t)(r + 3) * 1024 + cg] = acc[m][n][3] + bias;
    }
  }
}

extern "C" void kernel_launch(void* const* d_in, const int* in_sizes, int n_in,
                              void* d_out, int out_size, void* d_ws, size_t ws_size,
                              hipStream_t stream) {
  (void)in_sizes; (void)n_in; (void)out_size; (void)ws_size;
  const float* x  = (const float*)d_in[0];
  const float* Wq = (const float*)d_in[1];
  const float* bq = (const float*)d_in[2];
  const float* Wk = (const float*)d_in[3];
  const float* bk = (const float*)d_in[4];
  const float* Wv = (const float*)d_in[5];
  const float* bv = (const float*)d_in[6];
  const float* Wo = (const float*)d_in[7];
  const float* bo = (const float*)d_in[8];
  float* out = (float*)d_out;
  char* ws = (char*)d_ws;
  unsigned short* xb  = (unsigned short*)(ws);             // [4096][1024] bf16
  unsigned short* Wt  = (unsigned short*)(ws + 8388608);   // [Wq^T|Wk^T|Wv^T|Wo^T]
  unsigned short* Wot = (unsigned short*)(ws + 14680064);  // = Wt + 3*1048576
  unsigned short* qb  = (unsigned short*)(ws + 16777216);  // pre-scaled q
  unsigned short* kfb = (unsigned short*)(ws + 25165824);  // K fragment-order
  unsigned short* vfb = (unsigned short*)(ws + 33554432);  // V K=32 B-fragment order
  unsigned short* ao  = (unsigned short*)(ws + 41943040);  // [B,S,H,Dh] bf16

  prep<<<2048, 256, 0, stream>>>(x, Wq, Wk, Wv, Wo, xb, Wt);
  qkv_gemm<<<256, 512, 0, stream>>>(xb, Wt, bq, bk, bv, qb, kfb, vfb);
  attn_fwd<<<512, 256, 0, stream>>>(qb, kfb, vfb, ao);
  out_gemm<<<512, 256, 0, stream>>>(ao, Wot, bo, out);
}

// Round 16
// 99.931 us; speedup vs baseline: 1.0560x; 1.0108x over previous
//
#include <hip/hip_runtime.h>
#include <hip/hip_bf16.h>
#include <stdint.h>

using f32x4 = __attribute__((ext_vector_type(4))) float;
using s16x8 = __attribute__((ext_vector_type(8))) short;
using s16x4 = __attribute__((ext_vector_type(4))) short;

__device__ __forceinline__ unsigned short f2bf(float f) {
  union { float f; unsigned int u; } v; v.f = f;
  return (unsigned short)((v.u + 0x7FFFu + ((v.u >> 16) & 1u)) >> 16);
}

__device__ __forceinline__ float exp2_(float x) {
  float r;
  asm("v_exp_f32 %0, %1" : "=v"(r) : "v"(x));
  return r;
}

// pack 2 f32 -> u32 of 2 bf16 (lo=a, hi=b) via single v_cvt_pk_bf16_f32
__device__ __forceinline__ unsigned cvtpk(float a, float b) {
  unsigned r;
  asm("v_cvt_pk_bf16_f32 %0, %1, %2" : "=v"(r) : "v"(a), "v"(b));
  return r;
}

__device__ __forceinline__ short pbf(float f) {
  __hip_bfloat16 h = __float2bfloat16(f);
  return *(short*)&h;
}

#define GLD16(gp, lp) __builtin_amdgcn_global_load_lds( \
    (const __attribute__((address_space(1))) unsigned int*)(uintptr_t)(gp), \
    (__attribute__((address_space(3))) unsigned int*)(uintptr_t)(lp), 16, 0, 0)

__device__ __forceinline__ f32x4 mfma32(s16x8 a, s16x8 b, f32x4 c) {
  return __builtin_amdgcn_mfma_f32_16x16x32_bf16(a, b, c, 0, 0, 0);
}

// ---------------- prep: fused x-convert + 4 weight transposes ----------------
__global__ __launch_bounds__(256)
void prep(const float* __restrict__ x,
          const float* __restrict__ Wq, const float* __restrict__ Wk,
          const float* __restrict__ Wv, const float* __restrict__ Wo,
          unsigned short* __restrict__ xb, unsigned short* __restrict__ Wt) {
  __shared__ float tile[64][65];
  int blk = blockIdx.x;
  int tid = threadIdx.x;
  if (blk < 1024) {
    const float4* xi = (const float4*)x;
    ushort4* xo = (ushort4*)xb;
    #pragma unroll
    for (int j = 0; j < 4; ++j) {
      int i = blk * 1024 + j * 256 + tid;
      float4 v = xi[i];
      ushort4 o;
      o.x = f2bf(v.x); o.y = f2bf(v.y); o.z = f2bf(v.z); o.w = f2bf(v.w);
      xo[i] = o;
    }
  } else {
    int wid = blk - 1024;
    int which = wid >> 8, t = wid & 255;
    const float* W = (which == 0) ? Wq : (which == 1) ? Wk : (which == 2) ? Wv : Wo;
    unsigned short* dst = Wt + (size_t)which * 1048576;
    int k0 = (t & 15) * 64, n0 = (t >> 4) * 64;
    int tx = tid & 63, ty = tid >> 6;
    #pragma unroll
    for (int j = 0; j < 64; j += 4)
      tile[ty + j][tx] = W[(size_t)(k0 + ty + j) * 1024 + n0 + tx];
    __syncthreads();
    #pragma unroll
    for (int j = 0; j < 64; j += 4)
      dst[(size_t)(n0 + ty + j) * 1024 + k0 + tx] = f2bf(tile[tx][ty + j]);
  }
}

// ---------------- fused QKV GEMM: 256x192 tile, 8 waves, BK=64 (R14) ---------
// Double-buffer (2 x 57344B = 114.7KB; ring-3 would need 172KB > 160KB limit).
// Epilogue writes q (pre-scaled by log2e/8), K in K=32 A-fragment order, and
// V in K=32 B-fragment order for attention's mfma_16x16x32 PV.
__global__ __launch_bounds__(512, 2)
void qkv_gemm(const unsigned short* __restrict__ A,
              const unsigned short* __restrict__ Bt,
              const float* __restrict__ bq, const float* __restrict__ bk,
              const float* __restrict__ bv,
              unsigned short* __restrict__ qo, unsigned short* __restrict__ kf,
              unsigned short* __restrict__ vf) {
  __shared__ unsigned short lds2[2][28672];   // per buf: A 0..16383, B 16384..28671
  int orig = blockIdx.x;                      // 256 wgs
  int wg = (orig & 7) * 32 + (orig >> 3);
  int bm = wg >> 4, bn = wg & 15;
  int m0 = bm << 8;
  int n0 = bn * 192;
  int tid = threadIdx.x;
  int w = tid >> 6, ln = tid & 63;
  int g = ln >> 4, c = ln & 15;
  int wm = w >> 2, wn = w & 3;                // 2M x 4N waves; wave = 128x48

  int rrs = tid >> 3;
  int lcol = (((tid & 7) ^ ((tid >> 3) & 7)) << 4);
  const char* pA = (const char*)A + (size_t)(m0 + rrs) * 2048 + lcol;
  const char* pB = (const char*)Bt + (size_t)(n0 + rrs) * 2048 + lcol;
  int woff = w * 1024;

#define QKV_STAGE(buf, kt)                                                     \
  {                                                                            \
    char* db = (char*)&lds2[buf][0];                                           \
    _Pragma("unroll")                                                          \
    for (int s = 0; s < 4; ++s)                                                \
      GLD16(pA + (size_t)s * 131072 + (kt) * 128, db + s * 8192 + woff);       \
    _Pragma("unroll")                                                          \
    for (int s = 0; s < 3; ++s)                                                \
      GLD16(pB + (size_t)s * 131072 + (kt) * 128,                              \
            db + 32768 + s * 8192 + woff);                                     \
  }

  int cs = (c & 7) << 4;
#define DSFA(LA, mi, kk)                                                       \
  (*(const s16x8*)&(LA)[((mi) >> 2) * 4096 + (((mi) & 3) * 16 + c) * 64 +      \
                        ((((kk) * 64 + g * 16) ^ cs) >> 1)])
#define DSFB(LB, ni, kk)                                                       \
  (*(const s16x8*)&(LB)[((wn * 48 + (ni) * 16) >> 6) * 4096 +                  \
                        (((wn * 48 + (ni) * 16) & 63) + c) * 64 +              \
                        ((((kk) * 64 + g * 16) ^ cs) >> 1)])

  f32x4 acc[8][3];
  f32x4 zero = {0.f, 0.f, 0.f, 0.f};
  #pragma unroll
  for (int mi = 0; mi < 8; ++mi)
    #pragma unroll
    for (int ni = 0; ni < 3; ++ni) acc[mi][ni] = zero;

  QKV_STAGE(0, 0);
  asm volatile("s_waitcnt vmcnt(0)" ::: "memory");
  __builtin_amdgcn_s_barrier();

  for (int kt = 0; kt < 16; ++kt) {
    int bsel = kt & 1;
    const unsigned short* LA = &lds2[bsel][wm * 8192];
    const unsigned short* LB = &lds2[bsel][16384];
    if (kt < 15) QKV_STAGE(bsel ^ 1, kt + 1);

    s16x8 bfr[3][2];
    #pragma unroll
    for (int ni = 0; ni < 3; ++ni) {
      bfr[ni][0] = DSFB(LB, ni, 0);
      bfr[ni][1] = DSFB(LB, ni, 1);
    }
    s16x8 a[4][2];
    #pragma unroll
    for (int mi = 0; mi < 4; ++mi) {
      a[mi][0] = DSFA(LA, mi, 0);
      a[mi][1] = DSFA(LA, mi, 1);
    }
    __builtin_amdgcn_s_setprio(1);
    #pragma unroll
    for (int mi = 0; mi < 4; ++mi)
      #pragma unroll
      for (int ni = 0; ni < 3; ++ni) {
        acc[mi][ni] = mfma32(a[mi][0], bfr[ni][0], acc[mi][ni]);
        acc[mi][ni] = mfma32(a[mi][1], bfr[ni][1], acc[mi][ni]);
      }
    __builtin_amdgcn_s_setprio(0);
    #pragma unroll
    for (int mi = 0; mi < 4; ++mi) {
      a[mi][0] = DSFA(LA, mi + 4, 0);
      a[mi][1] = DSFA(LA, mi + 4, 1);
    }
    __builtin_amdgcn_s_setprio(1);
    #pragma unroll
    for (int mi = 0; mi < 4; ++mi)
      #pragma unroll
      for (int ni = 0; ni < 3; ++ni) {
        acc[mi + 4][ni] = mfma32(a[mi][0], bfr[ni][0], acc[mi + 4][ni]);
        acc[mi + 4][ni] = mfma32(a[mi][1], bfr[ni][1], acc[mi + 4][ni]);
      }
    __builtin_amdgcn_s_setprio(0);

    asm volatile("s_waitcnt vmcnt(0)" ::: "memory");
    __builtin_amdgcn_s_barrier();
  }
#undef QKV_STAGE
#undef DSFA
#undef DSFB

  #pragma unroll
  for (int ni = 0; ni < 3; ++ni) {
    int cg = n0 + wn * 48 + ni * 16 + c;    // 0..3071
    int p = cg >> 10;                        // 0=q 1=k 2=v
    int d = cg & 1023;
    int hh = d >> 6, dh = d & 63;
    const float* bp = (p == 0) ? bq : (p == 1) ? bk : bv;
    float bias = bp[d];
    #pragma unroll
    for (int mi = 0; mi < 8; ++mi) {
      int r = m0 + wm * 128 + mi * 16 + g * 4;  // rows r..r+3 (e=0..3)
      int b2 = r >> 11, s = r & 2047;
      size_t pv = (size_t)((b2 << 4) + hh);
      if (p == 2) {
        int ch = s >> 5;
        int l16 = ((s >> 3) & 3) * 16 + (dh & 15);
        int jo = s & 7;
        ushort4 pk;
        pk.x = f2bf(acc[mi][ni][0] + bias);
        pk.y = f2bf(acc[mi][ni][1] + bias);
        pk.z = f2bf(acc[mi][ni][2] + bias);
        pk.w = f2bf(acc[mi][ni][3] + bias);
        *(ushort4*)&vf[pv * 131072 +
                       (size_t)((ch * 4 + (dh >> 4)) * 64 + l16) * 8 + jo] = pk;
      } else if (p == 1) {
        int T = s >> 4;
        int h2 = dh >> 5, gp = (dh >> 3) & 3, j = dh & 7;
        unsigned short* kd = kf + pv * 131072 + T * 1024 + h2 * 512 +
                             (gp * 16 + (s & 15)) * 8 + j;
        kd[0]  = f2bf(acc[mi][ni][0] + bias);
        kd[8]  = f2bf(acc[mi][ni][1] + bias);
        kd[16] = f2bf(acc[mi][ni][2] + bias);
        kd[24] = f2bf(acc[mi][ni][3] + bias);
      } else {
        const float sc = 0.180336880111120f;  // 1/8 * log2(e)
        size_t base = (pv * 2048 + s) * 64 + dh;
        qo[base]       = f2bf((acc[mi][ni][0] + bias) * sc);
        qo[base + 64]  = f2bf((acc[mi][ni][1] + bias) * sc);
        qo[base + 128] = f2bf((acc[mi][ni][2] + bias) * sc);
        qo[base + 192] = f2bf((acc[mi][ni][3] + bias) * sc);
      }
    }
  }
}

// ---------------- flash attention (R14: quad-buffer ring, 1 barrier/iter) ----
__global__ __launch_bounds__(256, 2)
void attn_fwd(const unsigned short* __restrict__ q,
              const unsigned short* __restrict__ kfb,
              const unsigned short* __restrict__ vfb,
              unsigned short* __restrict__ ao) {
  __shared__ unsigned short ldsKV[4][8192];  // ring: per buf K 0..4095, V 4096..8191
  __shared__ unsigned short ldsP[4][2048];   // wave-private P scratch (4KB/wave)
  int orig = blockIdx.x;                    // 512 wgs
  int wg = (orig & 7) * 64 + (orig >> 3);   // XCD-contiguous
  int pair = wg >> 4, qt = wg & 15;
  int tid = threadIdx.x;
  int w = tid >> 6, ln = tid & 63;
  int g = ln >> 4, c = ln & 15;
  int q0 = qt * 128 + w * 32;
  const unsigned short* qp = q + (size_t)pair * 131072;
  const char* kbase = (const char*)(kfb + (size_t)pair * 131072);
  const char* vbase = (const char*)(vfb + (size_t)pair * 131072);

  const char* ssrc = ((w < 2) ? kbase : vbase) + (w & 1) * 4096;
  int dsto = (w >= 2 ? 8192 : 0) + (w & 1) * 4096;

  unsigned short* Pw = &ldsP[w][0];
  int pwbase = (g >> 1) * 128 + c * 8 + (g & 1) * 4;

  s16x8 qf[2][2];
  #pragma unroll
  for (int j = 0; j < 2; ++j)
    #pragma unroll
    for (int h = 0; h < 2; ++h)
      qf[j][h] = *(const s16x8*)&qp[(q0 + j * 16 + c) * 64 + h * 32 + g * 8];

  f32x4 acc[2][4];
  f32x4 zero = {0.f, 0.f, 0.f, 0.f};
  #pragma unroll
  for (int j = 0; j < 2; ++j)
    #pragma unroll
    for (int dt = 0; dt < 4; ++dt) acc[j][dt] = zero;
  float l0 = 0.f, l1 = 0.f;

  #pragma unroll
  for (int jj = 0; jj < 4; ++jj)
    GLD16(ssrc + jj * 1024 + ln * 16, (char*)&ldsKV[0][0] + dsto + jj * 1024);

  const unsigned short* L0 = ldsKV[0];
  const unsigned short* L1 = ldsKV[1];
  const unsigned short* L2 = ldsKV[2];
  const unsigned short* L3 = ldsKV[3];

#define ATTN_ITER(T, LC, LP, LN)                                               \
  {                                                                            \
    if ((T) < 31) {                                                            \
      const char* s2 = ssrc + (size_t)((T) + 1) * 8192;                        \
      char* d2 = (char*)(LN) + dsto;                                           \
      _Pragma("unroll")                                                        \
      for (int jj = 0; jj < 4; ++jj)                                           \
        GLD16(s2 + jj * 1024 + ln * 16, d2 + jj * 1024);                       \
      asm volatile("s_waitcnt vmcnt(4)" ::: "memory");                         \
    } else {                                                                   \
      asm volatile("s_waitcnt vmcnt(0)" ::: "memory");                         \
    }                                                                          \
    __builtin_amdgcn_s_barrier();                                              \
    s16x8 kc[4][2];                                                            \
    _Pragma("unroll")                                                          \
    for (int kt = 0; kt < 4; ++kt) {                                           \
      kc[kt][0] = *(const s16x8*)&(LC)[kt * 1024 + ln * 8];                    \
      kc[kt][1] = *(const s16x8*)&(LC)[kt * 1024 + 512 + ln * 8];              \
    }                                                                          \
    f32x4 st[4][2];                                                            \
    __builtin_amdgcn_s_setprio(1);                                             \
    _Pragma("unroll")                                                          \
    for (int kt = 0; kt < 4; ++kt)                                             \
      _Pragma("unroll")                                                        \
      for (int j = 0; j < 2; ++j) {                                            \
        f32x4 t2 = zero;                                                       \
        t2 = mfma32(kc[kt][0], qf[j][0], t2);                                  \
        t2 = mfma32(kc[kt][1], qf[j][1], t2);                                  \
        st[kt][j] = t2;                                                        \
      }                                                                        \
    __builtin_amdgcn_s_setprio(0);                                             \
    if ((T) > 0) {                                                             \
      s16x8 pa00 = *(const s16x8*)&Pw[ln * 8];                                 \
      s16x8 pa01 = *(const s16x8*)&Pw[512 + ln * 8];                           \
      s16x8 pa10 = *(const s16x8*)&Pw[1024 + ln * 8];                          \
      s16x8 pa11 = *(const s16x8*)&Pw[1536 + ln * 8];                          \
      __builtin_amdgcn_s_setprio(1);                                           \
      _Pragma("unroll")                                                        \
      for (int m = 0; m < 2; ++m)                                              \
        _Pragma("unroll")                                                      \
        for (int dt = 0; dt < 4; ++dt) {                                       \
          s16x8 vv = *(const s16x8*)&(LP)[4096 + m * 2048 + dt * 512 + ln * 8];\
          acc[0][dt] = mfma32(m ? pa01 : pa00, vv, acc[0][dt]);                \
          acc[1][dt] = mfma32(m ? pa11 : pa10, vv, acc[1][dt]);                \
        }                                                                      \
      __builtin_amdgcn_s_setprio(0);                                           \
    }                                                                          \
    _Pragma("unroll")                                                          \
    for (int kt = 0; kt < 4; ++kt) {                                           \
      float p00 = exp2_(st[kt][0][0]), p01 = exp2_(st[kt][0][1]);              \
      float p02 = exp2_(st[kt][0][2]), p03 = exp2_(st[kt][0][3]);              \
      float p10 = exp2_(st[kt][1][0]), p11 = exp2_(st[kt][1][1]);              \
      float p12 = exp2_(st[kt][1][2]), p13 = exp2_(st[kt][1][3]);              \
      l0 += (p00 + p01) + (p02 + p03);                                         \
      l1 += (p10 + p11) + (p12 + p13);                                         \
      int wa = (kt >> 1) * 512 + (kt & 1) * 256 + pwbase;                      \
      uint2 w0; w0.x = cvtpk(p00, p01); w0.y = cvtpk(p02, p03);                \
      *(uint2*)&Pw[wa] = w0;                                                   \
      uint2 w1; w1.x = cvtpk(p10, p11); w1.y = cvtpk(p12, p13);                \
      *(uint2*)&Pw[1024 + wa] = w1;                                            \
    }                                                                          \
  }

  for (int t = 0; t < 32; t += 4) {
    ATTN_ITER(t,     L0, L3, L1);
    ATTN_ITER(t + 1, L1, L0, L2);
    ATTN_ITER(t + 2, L2, L1, L3);
    ATTN_ITER(t + 3, L3, L2, L0);
  }
#undef ATTN_ITER

  {
    s16x8 pa00 = *(const s16x8*)&Pw[ln * 8];
    s16x8 pa01 = *(const s16x8*)&Pw[512 + ln * 8];
    s16x8 pa10 = *(const s16x8*)&Pw[1024 + ln * 8];
    s16x8 pa11 = *(const s16x8*)&Pw[1536 + ln * 8];
    __builtin_amdgcn_s_setprio(1);
    #pragma unroll
    for (int m = 0; m < 2; ++m)
      #pragma unroll
      for (int dt = 0; dt < 4; ++dt) {
        s16x8 vv = *(const s16x8*)&L3[4096 + m * 2048 + dt * 512 + ln * 8];
        acc[0][dt] = mfma32(m ? pa01 : pa00, vv, acc[0][dt]);
        acc[1][dt] = mfma32(m ? pa11 : pa10, vv, acc[1][dt]);
      }
    __builtin_amdgcn_s_setprio(0);
  }

  l0 += __shfl_xor(l0, 16); l0 += __shfl_xor(l0, 32);
  l1 += __shfl_xor(l1, 16); l1 += __shfl_xor(l1, 32);
  float li0 = 1.f / l0, li1 = 1.f / l1;
  int b = pair >> 4, hh = pair & 15;
  #pragma unroll
  for (int e = 0; e < 4; ++e) {
    float i0 = __shfl(li0, g * 4 + e);
    float i1 = __shfl(li1, g * 4 + e);
    size_t r0 = ((size_t)(b * 2048 + q0 + g * 4 + e) * 16 + hh) * 64;
    size_t r1 = ((size_t)(b * 2048 + q0 + 16 + g * 4 + e) * 16 + hh) * 64;
    #pragma unroll
    for (int dt = 0; dt < 4; ++dt) {
      ao[r0 + dt * 16 + c] = (unsigned short)pbf(acc[0][dt][e] * i0);
      ao[r1 + dt * 16 + c] = (unsigned short)pbf(acc[1][dt][e] * i1);
    }
  }
}

// ---------------- output GEMM: 64x128 tile, BK=64, RING-3, swizzled ----------
// ao[4096,1024] x Wot -> fp32 out. BK 32->64 halves iteration count (16
// iters); 3-buffer ring (3 x 24576B = 73.7KB -> 2 blocks/CU) + uniform
// vmcnt(6) + ONE barrier/iter (T4 counted); qkv-style XOR swizzle (BK=64 rows
// are 128B-strided -> 16-way conflict without it): pre-swizzled global source
// + swizzled ds_read. Ascending-k accumulation -> bitwise-identical output.
__global__ __launch_bounds__(256, 2)
void out_gemm(const unsigned short* __restrict__ A,
              const unsigned short* __restrict__ Bt,
              const float* __restrict__ bo, float* __restrict__ out) {
  __shared__ unsigned short lds[3][12288];  // per buf: A [64][64] @0, B [128][64] @4096
  int orig = blockIdx.x;                    // 512 wgs
  int wg = (orig & 7) * 64 + (orig >> 3);
  int bm = wg >> 3, bn = wg & 7;
  int m0 = bm << 6, n0 = bn << 7;
  int tid = threadIdx.x;
  int w = tid >> 6, ln = tid & 63;
  int g = ln >> 4, c = ln & 15;
  int wr = w >> 1, wc = w & 1;

  int rrs = tid >> 3;                       // 0..31
  int lcol = (((tid & 7) ^ ((tid >> 3) & 7)) << 4);
  const char* pA = (const char*)A + (size_t)(m0 + rrs) * 2048 + lcol;
  const char* pB = (const char*)Bt + (size_t)(n0 + rrs) * 2048 + lcol;
  int woff = w * 1024;

#define OUT_STAGE(buf, kt)                                                     \
  {                                                                            \
    char* db = (char*)&lds[buf][0];                                            \
    _Pragma("unroll")                                                          \
    for (int s = 0; s < 2; ++s)                                                \
      GLD16(pA + (size_t)s * 65536 + (kt) * 128, db + s * 4096 + woff);        \
    _Pragma("unroll")                                                          \
    for (int s = 0; s < 4; ++s)                                                \
      GLD16(pB + (size_t)s * 65536 + (kt) * 128, db + 8192 + s * 4096 + woff); \
  }

  int cs = (c & 7) << 4;
#define ODSA(L, mi, kk)                                                        \
  (*(const s16x8*)&(L)[(wr * 32 + (mi) * 16 + c) * 64 +                        \
                       ((((kk) * 64 + g * 16) ^ cs) >> 1)])
#define ODSB(L, ni, kk)                                                        \
  (*(const s16x8*)&(L)[4096 + (wc * 64 + (ni) * 16 + c) * 64 +                 \
                       ((((kk) * 64 + g * 16) ^ cs) >> 1)])

  f32x4 acc[2][4];
  f32x4 zero = {0.f, 0.f, 0.f, 0.f};
  #pragma unroll
  for (int m = 0; m < 2; ++m)
    #pragma unroll
    for (int n = 0; n < 4; ++n) acc[m][n] = zero;

  OUT_STAGE(0, 0);
  OUT_STAGE(1, 1);

  for (int t = 0; t < 16; ++t) {
    int bsel = t % 3;
    const unsigned short* L = &lds[bsel][0];
    if (t < 15) {
      asm volatile("s_waitcnt vmcnt(6)" ::: "memory");
    } else {
      asm volatile("s_waitcnt vmcnt(0)" ::: "memory");
    }
    __builtin_amdgcn_s_barrier();
    if (t < 14) OUT_STAGE((t + 2) % 3, t + 2);

    s16x8 af[2][2], bf[4][2];
    #pragma unroll
    for (int m = 0; m < 2; ++m) {
      af[m][0] = ODSA(L, m, 0);
      af[m][1] = ODSA(L, m, 1);
    }
    #pragma unroll
    for (int n = 0; n < 4; ++n) {
      bf[n][0] = ODSB(L, n, 0);
      bf[n][1] = ODSB(L, n, 1);
    }
    __builtin_amdgcn_s_setprio(1);
    #pragma unroll
    for (int m = 0; m < 2; ++m)
      #pragma unroll
      for (int n = 0; n < 4; ++n) {
        acc[m][n] = mfma32(af[m][0], bf[n][0], acc[m][n]);
        acc[m][n] = mfma32(af[m][1], bf[n][1], acc[m][n]);
      }
    __builtin_amdgcn_s_setprio(0);
  }
#undef OUT_STAGE
#undef ODSA
#undef ODSB

  #pragma unroll
  for (int n = 0; n < 4; ++n) {
    int cg = n0 + wc * 64 + n * 16 + c;
    float bias = bo[cg];
    #pragma unroll
    for (int m = 0; m < 2; ++m) {
      int r = m0 + wr * 32 + m * 16 + g * 4;
      out[(size_t)r * 1024 + cg] = acc[m][n][0] + bias;
      out[(size_t)(r + 1) * 1024 + cg] = acc[m][n][1] + bias;
      out[(size_t)(r + 2) * 1024 + cg] = acc[m][n][2] + bias;
      out[(size_t)(r + 3) * 1024 + cg] = acc[m][n][3] + bias;
    }
  }
}

extern "C" void kernel_launch(void* const* d_in, const int* in_sizes, int n_in,
                              void* d_out, int out_size, void* d_ws, size_t ws_size,
                              hipStream_t stream) {
  (void)in_sizes; (void)n_in; (void)out_size; (void)ws_size;
  const float* x  = (const float*)d_in[0];
  const float* Wq = (const float*)d_in[1];
  const float* bq = (const float*)d_in[2];
  const float* Wk = (const float*)d_in[3];
  const float* bk = (const float*)d_in[4];
  const float* Wv = (const float*)d_in[5];
  const float* bv = (const float*)d_in[6];
  const float* Wo = (const float*)d_in[7];
  const float* bo = (const float*)d_in[8];
  float* out = (float*)d_out;
  char* ws = (char*)d_ws;
  unsigned short* xb  = (unsigned short*)(ws);             // [4096][1024] bf16
  unsigned short* Wt  = (unsigned short*)(ws + 8388608);   // [Wq^T|Wk^T|Wv^T|Wo^T]
  unsigned short* Wot = (unsigned short*)(ws + 14680064);  // = Wt + 3*1048576
  unsigned short* qb  = (unsigned short*)(ws + 16777216);  // pre-scaled q
  unsigned short* kfb = (unsigned short*)(ws + 25165824);  // K fragment-order
  unsigned short* vfb = (unsigned short*)(ws + 33554432);  // V K=32 B-fragment order
  unsigned short* ao  = (unsigned short*)(ws + 41943040);  // [B,S,H,Dh] bf16

  prep<<<2048, 256, 0, stream>>>(x, Wq, Wk, Wv, Wo, xb, Wt);
  qkv_gemm<<<256, 512, 0, stream>>>(xb, Wt, bq, bk, bv, qb, kfb, vfb);
  attn_fwd<<<512, 256, 0, stream>>>(qb, kfb, vfb, ao);
  out_gemm<<<512, 256, 0, stream>>>(ao, Wot, bo, out);
}

// Round 17
// 99.496 us; speedup vs baseline: 1.0606x; 1.0044x over previous
//
#include <hip/hip_runtime.h>
#include <hip/hip_bf16.h>
#include <stdint.h>

using f32x4 = __attribute__((ext_vector_type(4))) float;
using s16x8 = __attribute__((ext_vector_type(8))) short;
using s16x4 = __attribute__((ext_vector_type(4))) short;

__device__ __forceinline__ unsigned short f2bf(float f) {
  union { float f; unsigned int u; } v; v.f = f;
  return (unsigned short)((v.u + 0x7FFFu + ((v.u >> 16) & 1u)) >> 16);
}

__device__ __forceinline__ float exp2_(float x) {
  float r;
  asm("v_exp_f32 %0, %1" : "=v"(r) : "v"(x));
  return r;
}

// pack 2 f32 -> u32 of 2 bf16 (lo=a, hi=b) via single v_cvt_pk_bf16_f32
__device__ __forceinline__ unsigned cvtpk(float a, float b) {
  unsigned r;
  asm("v_cvt_pk_bf16_f32 %0, %1, %2" : "=v"(r) : "v"(a), "v"(b));
  return r;
}

__device__ __forceinline__ short pbf(float f) {
  __hip_bfloat16 h = __float2bfloat16(f);
  return *(short*)&h;
}

#define GLD16(gp, lp) __builtin_amdgcn_global_load_lds( \
    (const __attribute__((address_space(1))) unsigned int*)(uintptr_t)(gp), \
    (__attribute__((address_space(3))) unsigned int*)(uintptr_t)(lp), 16, 0, 0)

__device__ __forceinline__ f32x4 mfma32(s16x8 a, s16x8 b, f32x4 c) {
  return __builtin_amdgcn_mfma_f32_16x16x32_bf16(a, b, c, 0, 0, 0);
}

// ---------------- prep: fused x-convert + 4 weight transposes ----------------
__global__ __launch_bounds__(256)
void prep(const float* __restrict__ x,
          const float* __restrict__ Wq, const float* __restrict__ Wk,
          const float* __restrict__ Wv, const float* __restrict__ Wo,
          unsigned short* __restrict__ xb, unsigned short* __restrict__ Wt) {
  __shared__ float tile[64][65];
  int blk = blockIdx.x;
  int tid = threadIdx.x;
  if (blk < 1024) {
    const float4* xi = (const float4*)x;
    ushort4* xo = (ushort4*)xb;
    #pragma unroll
    for (int j = 0; j < 4; ++j) {
      int i = blk * 1024 + j * 256 + tid;
      float4 v = xi[i];
      ushort4 o;
      o.x = f2bf(v.x); o.y = f2bf(v.y); o.z = f2bf(v.z); o.w = f2bf(v.w);
      xo[i] = o;
    }
  } else {
    int wid = blk - 1024;
    int which = wid >> 8, t = wid & 255;
    const float* W = (which == 0) ? Wq : (which == 1) ? Wk : (which == 2) ? Wv : Wo;
    unsigned short* dst = Wt + (size_t)which * 1048576;
    int k0 = (t & 15) * 64, n0 = (t >> 4) * 64;
    int tx = tid & 63, ty = tid >> 6;
    #pragma unroll
    for (int j = 0; j < 64; j += 4)
      tile[ty + j][tx] = W[(size_t)(k0 + ty + j) * 1024 + n0 + tx];
    __syncthreads();
    #pragma unroll
    for (int j = 0; j < 64; j += 4)
      dst[(size_t)(n0 + ty + j) * 1024 + k0 + tx] = f2bf(tile[tx][ty + j]);
  }
}

// ---------------- fused QKV GEMM: 128x192 tile, 8 waves, BK=64 ---------------
// Retiled from 256x192 for TLP: grid 512 = 2 blocks/CU = 4 waves/SIMD (was 2).
// Per-SIMD window accounting showed the 2-wave config ~75% stalled (same
// signature attn had); pure-GEMM waves co-schedule (m114), so doubling TLP
// should halve the latency-exposure share. LDS per buf: A[128][64]=16KB +
// B[192][64]=24KB = 40KB; dbuf 80KB -> 2 blocks = 160KB exactly. Wave=64x48
// (acc 4x3). Same BK=64 XOR-swizzle pair, same GLD16 dbuf staging, same
// epilogue scatter (q pre-scaled, K in K=32 A-frag, V in K=32 B-frag order),
// same ascending-k accumulation -> bitwise-identical outputs.
__global__ __launch_bounds__(512, 4)
void qkv_gemm(const unsigned short* __restrict__ A,
              const unsigned short* __restrict__ Bt,
              const float* __restrict__ bq, const float* __restrict__ bk,
              const float* __restrict__ bv,
              unsigned short* __restrict__ qo, unsigned short* __restrict__ kf,
              unsigned short* __restrict__ vf) {
  __shared__ unsigned short lds2[2][20480];   // per buf: A 0..8191, B 8192..20479
  int orig = blockIdx.x;                      // 512 wgs
  int wg = (orig & 7) * 64 + (orig >> 3);
  int bm = wg >> 4, bn = wg & 15;             // bm 0..31, bn 0..15
  int m0 = bm << 7;
  int n0 = bn * 192;
  int tid = threadIdx.x;
  int w = tid >> 6, ln = tid & 63;
  int g = ln >> 4, c = ln & 15;
  int wm = w >> 2, wn = w & 3;                // 2M x 4N waves; wave = 64x48

  int rrs = tid >> 3;                         // 0..63
  int lcol = (((tid & 7) ^ ((tid >> 3) & 7)) << 4);
  const char* pA = (const char*)A + (size_t)(m0 + rrs) * 2048 + lcol;
  const char* pB = (const char*)Bt + (size_t)(n0 + rrs) * 2048 + lcol;
  int woff = w * 1024;

#define QKV_STAGE(buf, kt)                                                     \
  {                                                                            \
    char* db = (char*)&lds2[buf][0];                                           \
    _Pragma("unroll")                                                          \
    for (int s = 0; s < 2; ++s)                                                \
      GLD16(pA + (size_t)s * 131072 + (kt) * 128, db + s * 8192 + woff);       \
    _Pragma("unroll")                                                          \
    for (int s = 0; s < 3; ++s)                                                \
      GLD16(pB + (size_t)s * 131072 + (kt) * 128,                              \
            db + 16384 + s * 8192 + woff);                                     \
  }

  int cs = (c & 7) << 4;
  // A: wave wm owns 64-row subtile wm (4096 ushorts each)
#define DSFA(LA, mi, kk)                                                       \
  (*(const s16x8*)&(LA)[((mi) * 16 + c) * 64 +                                 \
                        ((((kk) * 64 + g * 16) ^ cs) >> 1)])
  // B: rows wn*48 + ni*16 within 192 (3 x 64-row subtiles of 4096 ushorts)
#define DSFB(LB, ni, kk)                                                       \
  (*(const s16x8*)&(LB)[((wn * 48 + (ni) * 16) >> 6) * 4096 +                  \
                        (((wn * 48 + (ni) * 16) & 63) + c) * 64 +              \
                        ((((kk) * 64 + g * 16) ^ cs) >> 1)])

  f32x4 acc[4][3];
  f32x4 zero = {0.f, 0.f, 0.f, 0.f};
  #pragma unroll
  for (int mi = 0; mi < 4; ++mi)
    #pragma unroll
    for (int ni = 0; ni < 3; ++ni) acc[mi][ni] = zero;

  QKV_STAGE(0, 0);
  asm volatile("s_waitcnt vmcnt(0)" ::: "memory");
  __builtin_amdgcn_s_barrier();

  for (int kt = 0; kt < 16; ++kt) {
    int bsel = kt & 1;
    const unsigned short* LA = &lds2[bsel][wm * 4096];
    const unsigned short* LB = &lds2[bsel][8192];
    if (kt < 15) QKV_STAGE(bsel ^ 1, kt + 1);

    s16x8 bfr[3][2];
    #pragma unroll
    for (int ni = 0; ni < 3; ++ni) {
      bfr[ni][0] = DSFB(LB, ni, 0);
      bfr[ni][1] = DSFB(LB, ni, 1);
    }
    s16x8 a[4][2];
    #pragma unroll
    for (int mi = 0; mi < 4; ++mi) {
      a[mi][0] = DSFA(LA, mi, 0);
      a[mi][1] = DSFA(LA, mi, 1);
    }
    __builtin_amdgcn_s_setprio(1);
    #pragma unroll
    for (int mi = 0; mi < 4; ++mi)
      #pragma unroll
      for (int ni = 0; ni < 3; ++ni) {
        acc[mi][ni] = mfma32(a[mi][0], bfr[ni][0], acc[mi][ni]);
        acc[mi][ni] = mfma32(a[mi][1], bfr[ni][1], acc[mi][ni]);
      }
    __builtin_amdgcn_s_setprio(0);

    asm volatile("s_waitcnt vmcnt(0)" ::: "memory");
    __builtin_amdgcn_s_barrier();
  }
#undef QKV_STAGE
#undef DSFA
#undef DSFB

  #pragma unroll
  for (int ni = 0; ni < 3; ++ni) {
    int cg = n0 + wn * 48 + ni * 16 + c;    // 0..3071
    int p = cg >> 10;                        // 0=q 1=k 2=v
    int d = cg & 1023;
    int hh = d >> 6, dh = d & 63;
    const float* bp = (p == 0) ? bq : (p == 1) ? bk : bv;
    float bias = bp[d];
    #pragma unroll
    for (int mi = 0; mi < 4; ++mi) {
      int r = m0 + wm * 64 + mi * 16 + g * 4;  // rows r..r+3 (e=0..3)
      int b2 = r >> 11, s = r & 2047;
      size_t pv = (size_t)((b2 << 4) + hh);
      if (p == 2) {
        int ch = s >> 5;
        int l16 = ((s >> 3) & 3) * 16 + (dh & 15);
        int jo = s & 7;
        ushort4 pk;
        pk.x = f2bf(acc[mi][ni][0] + bias);
        pk.y = f2bf(acc[mi][ni][1] + bias);
        pk.z = f2bf(acc[mi][ni][2] + bias);
        pk.w = f2bf(acc[mi][ni][3] + bias);
        *(ushort4*)&vf[pv * 131072 +
                       (size_t)((ch * 4 + (dh >> 4)) * 64 + l16) * 8 + jo] = pk;
      } else if (p == 1) {
        int T = s >> 4;
        int h2 = dh >> 5, gp = (dh >> 3) & 3, j = dh & 7;
        unsigned short* kd = kf + pv * 131072 + T * 1024 + h2 * 512 +
                             (gp * 16 + (s & 15)) * 8 + j;
        kd[0]  = f2bf(acc[mi][ni][0] + bias);
        kd[8]  = f2bf(acc[mi][ni][1] + bias);
        kd[16] = f2bf(acc[mi][ni][2] + bias);
        kd[24] = f2bf(acc[mi][ni][3] + bias);
      } else {
        const float sc = 0.180336880111120f;  // 1/8 * log2(e)
        size_t base = (pv * 2048 + s) * 64 + dh;
        qo[base]       = f2bf((acc[mi][ni][0] + bias) * sc);
        qo[base + 64]  = f2bf((acc[mi][ni][1] + bias) * sc);
        qo[base + 128] = f2bf((acc[mi][ni][2] + bias) * sc);
        qo[base + 192] = f2bf((acc[mi][ni][3] + bias) * sc);
      }
    }
  }
}

// ---------------- flash attention (R14: quad-buffer ring, 1 barrier/iter) ----
__global__ __launch_bounds__(256, 2)
void attn_fwd(const unsigned short* __restrict__ q,
              const unsigned short* __restrict__ kfb,
              const unsigned short* __restrict__ vfb,
              unsigned short* __restrict__ ao) {
  __shared__ unsigned short ldsKV[4][8192];  // ring: per buf K 0..4095, V 4096..8191
  __shared__ unsigned short ldsP[4][2048];   // wave-private P scratch (4KB/wave)
  int orig = blockIdx.x;                    // 512 wgs
  int wg = (orig & 7) * 64 + (orig >> 3);   // XCD-contiguous
  int pair = wg >> 4, qt = wg & 15;
  int tid = threadIdx.x;
  int w = tid >> 6, ln = tid & 63;
  int g = ln >> 4, c = ln & 15;
  int q0 = qt * 128 + w * 32;
  const unsigned short* qp = q + (size_t)pair * 131072;
  const char* kbase = (const char*)(kfb + (size_t)pair * 131072);
  const char* vbase = (const char*)(vfb + (size_t)pair * 131072);

  const char* ssrc = ((w < 2) ? kbase : vbase) + (w & 1) * 4096;
  int dsto = (w >= 2 ? 8192 : 0) + (w & 1) * 4096;

  unsigned short* Pw = &ldsP[w][0];
  int pwbase = (g >> 1) * 128 + c * 8 + (g & 1) * 4;

  s16x8 qf[2][2];
  #pragma unroll
  for (int j = 0; j < 2; ++j)
    #pragma unroll
    for (int h = 0; h < 2; ++h)
      qf[j][h] = *(const s16x8*)&qp[(q0 + j * 16 + c) * 64 + h * 32 + g * 8];

  f32x4 acc[2][4];
  f32x4 zero = {0.f, 0.f, 0.f, 0.f};
  #pragma unroll
  for (int j = 0; j < 2; ++j)
    #pragma unroll
    for (int dt = 0; dt < 4; ++dt) acc[j][dt] = zero;
  float l0 = 0.f, l1 = 0.f;

  #pragma unroll
  for (int jj = 0; jj < 4; ++jj)
    GLD16(ssrc + jj * 1024 + ln * 16, (char*)&ldsKV[0][0] + dsto + jj * 1024);

  const unsigned short* L0 = ldsKV[0];
  const unsigned short* L1 = ldsKV[1];
  const unsigned short* L2 = ldsKV[2];
  const unsigned short* L3 = ldsKV[3];

#define ATTN_ITER(T, LC, LP, LN)                                               \
  {                                                                            \
    if ((T) < 31) {                                                            \
      const char* s2 = ssrc + (size_t)((T) + 1) * 8192;                        \
      char* d2 = (char*)(LN) + dsto;                                           \
      _Pragma("unroll")                                                        \
      for (int jj = 0; jj < 4; ++jj)                                           \
        GLD16(s2 + jj * 1024 + ln * 16, d2 + jj * 1024);                       \
      asm volatile("s_waitcnt vmcnt(4)" ::: "memory");                         \
    } else {                                                                   \
      asm volatile("s_waitcnt vmcnt(0)" ::: "memory");                         \
    }                                                                          \
    __builtin_amdgcn_s_barrier();                                              \
    s16x8 kc[4][2];                                                            \
    _Pragma("unroll")                                                          \
    for (int kt = 0; kt < 4; ++kt) {                                           \
      kc[kt][0] = *(const s16x8*)&(LC)[kt * 1024 + ln * 8];                    \
      kc[kt][1] = *(const s16x8*)&(LC)[kt * 1024 + 512 + ln * 8];              \
    }                                                                          \
    f32x4 st[4][2];                                                            \
    __builtin_amdgcn_s_setprio(1);                                             \
    _Pragma("unroll")                                                          \
    for (int kt = 0; kt < 4; ++kt)                                             \
      _Pragma("unroll")                                                        \
      for (int j = 0; j < 2; ++j) {                                            \
        f32x4 t2 = zero;                                                       \
        t2 = mfma32(kc[kt][0], qf[j][0], t2);                                  \
        t2 = mfma32(kc[kt][1], qf[j][1], t2);                                  \
        st[kt][j] = t2;                                                        \
      }                                                                        \
    __builtin_amdgcn_s_setprio(0);                                             \
    if ((T) > 0) {                                                             \
      s16x8 pa00 = *(const s16x8*)&Pw[ln * 8];                                 \
      s16x8 pa01 = *(const s16x8*)&Pw[512 + ln * 8];                           \
      s16x8 pa10 = *(const s16x8*)&Pw[1024 + ln * 8];                          \
      s16x8 pa11 = *(const s16x8*)&Pw[1536 + ln * 8];                          \
      __builtin_amdgcn_s_setprio(1);                                           \
      _Pragma("unroll")                                                        \
      for (int m = 0; m < 2; ++m)                                              \
        _Pragma("unroll")                                                      \
        for (int dt = 0; dt < 4; ++dt) {                                       \
          s16x8 vv = *(const s16x8*)&(LP)[4096 + m * 2048 + dt * 512 + ln * 8];\
          acc[0][dt] = mfma32(m ? pa01 : pa00, vv, acc[0][dt]);                \
          acc[1][dt] = mfma32(m ? pa11 : pa10, vv, acc[1][dt]);                \
        }                                                                      \
      __builtin_amdgcn_s_setprio(0);                                           \
    }                                                                          \
    _Pragma("unroll")                                                          \
    for (int kt = 0; kt < 4; ++kt) {                                           \
      float p00 = exp2_(st[kt][0][0]), p01 = exp2_(st[kt][0][1]);              \
      float p02 = exp2_(st[kt][0][2]), p03 = exp2_(st[kt][0][3]);              \
      float p10 = exp2_(st[kt][1][0]), p11 = exp2_(st[kt][1][1]);              \
      float p12 = exp2_(st[kt][1][2]), p13 = exp2_(st[kt][1][3]);              \
      l0 += (p00 + p01) + (p02 + p03);                                         \
      l1 += (p10 + p11) + (p12 + p13);                                         \
      int wa = (kt >> 1) * 512 + (kt & 1) * 256 + pwbase;                      \
      uint2 w0; w0.x = cvtpk(p00, p01); w0.y = cvtpk(p02, p03);                \
      *(uint2*)&Pw[wa] = w0;                                                   \
      uint2 w1; w1.x = cvtpk(p10, p11); w1.y = cvtpk(p12, p13);                \
      *(uint2*)&Pw[1024 + wa] = w1;                                            \
    }                                                                          \
  }

  for (int t = 0; t < 32; t += 4) {
    ATTN_ITER(t,     L0, L3, L1);
    ATTN_ITER(t + 1, L1, L0, L2);
    ATTN_ITER(t + 2, L2, L1, L3);
    ATTN_ITER(t + 3, L3, L2, L0);
  }
#undef ATTN_ITER

  {
    s16x8 pa00 = *(const s16x8*)&Pw[ln * 8];
    s16x8 pa01 = *(const s16x8*)&Pw[512 + ln * 8];
    s16x8 pa10 = *(const s16x8*)&Pw[1024 + ln * 8];
    s16x8 pa11 = *(const s16x8*)&Pw[1536 + ln * 8];
    __builtin_amdgcn_s_setprio(1);
    #pragma unroll
    for (int m = 0; m < 2; ++m)
      #pragma unroll
      for (int dt = 0; dt < 4; ++dt) {
        s16x8 vv = *(const s16x8*)&L3[4096 + m * 2048 + dt * 512 + ln * 8];
        acc[0][dt] = mfma32(m ? pa01 : pa00, vv, acc[0][dt]);
        acc[1][dt] = mfma32(m ? pa11 : pa10, vv, acc[1][dt]);
      }
    __builtin_amdgcn_s_setprio(0);
  }

  l0 += __shfl_xor(l0, 16); l0 += __shfl_xor(l0, 32);
  l1 += __shfl_xor(l1, 16); l1 += __shfl_xor(l1, 32);
  float li0 = 1.f / l0, li1 = 1.f / l1;
  int b = pair >> 4, hh = pair & 15;
  #pragma unroll
  for (int e = 0; e < 4; ++e) {
    float i0 = __shfl(li0, g * 4 + e);
    float i1 = __shfl(li1, g * 4 + e);
    size_t r0 = ((size_t)(b * 2048 + q0 + g * 4 + e) * 16 + hh) * 64;
    size_t r1 = ((size_t)(b * 2048 + q0 + 16 + g * 4 + e) * 16 + hh) * 64;
    #pragma unroll
    for (int dt = 0; dt < 4; ++dt) {
      ao[r0 + dt * 16 + c] = (unsigned short)pbf(acc[0][dt][e] * i0);
      ao[r1 + dt * 16 + c] = (unsigned short)pbf(acc[1][dt][e] * i1);
    }
  }
}

// ---------------- output GEMM: 64x128 tile, BK=64, RING-3, swizzled ----------
__global__ __launch_bounds__(256, 2)
void out_gemm(const unsigned short* __restrict__ A,
              const unsigned short* __restrict__ Bt,
              const float* __restrict__ bo, float* __restrict__ out) {
  __shared__ unsigned short lds[3][12288];  // per buf: A [64][64] @0, B [128][64] @4096
  int orig = blockIdx.x;                    // 512 wgs
  int wg = (orig & 7) * 64 + (orig >> 3);
  int bm = wg >> 3, bn = wg & 7;
  int m0 = bm << 6, n0 = bn << 7;
  int tid = threadIdx.x;
  int w = tid >> 6, ln = tid & 63;
  int g = ln >> 4, c = ln & 15;
  int wr = w >> 1, wc = w & 1;

  int rrs = tid >> 3;                       // 0..31
  int lcol = (((tid & 7) ^ ((tid >> 3) & 7)) << 4);
  const char* pA = (const char*)A + (size_t)(m0 + rrs) * 2048 + lcol;
  const char* pB = (const char*)Bt + (size_t)(n0 + rrs) * 2048 + lcol;
  int woff = w * 1024;

#define OUT_STAGE(buf, kt)                                                     \
  {                                                                            \
    char* db = (char*)&lds[buf][0];                                            \
    _Pragma("unroll")                                                          \
    for (int s = 0; s < 2; ++s)                                                \
      GLD16(pA + (size_t)s * 65536 + (kt) * 128, db + s * 4096 + woff);        \
    _Pragma("unroll")                                                          \
    for (int s = 0; s < 4; ++s)                                                \
      GLD16(pB + (size_t)s * 65536 + (kt) * 128, db + 8192 + s * 4096 + woff); \
  }

  int cs = (c & 7) << 4;
#define ODSA(L, mi, kk)                                                        \
  (*(const s16x8*)&(L)[(wr * 32 + (mi) * 16 + c) * 64 +                        \
                       ((((kk) * 64 + g * 16) ^ cs) >> 1)])
#define ODSB(L, ni, kk)                                                        \
  (*(const s16x8*)&(L)[4096 + (wc * 64 + (ni) * 16 + c) * 64 +                 \
                       ((((kk) * 64 + g * 16) ^ cs) >> 1)])

  f32x4 acc[2][4];
  f32x4 zero = {0.f, 0.f, 0.f, 0.f};
  #pragma unroll
  for (int m = 0; m < 2; ++m)
    #pragma unroll
    for (int n = 0; n < 4; ++n) acc[m][n] = zero;

  OUT_STAGE(0, 0);
  OUT_STAGE(1, 1);

  for (int t = 0; t < 16; ++t) {
    int bsel = t % 3;
    const unsigned short* L = &lds[bsel][0];
    if (t < 15) {
      asm volatile("s_waitcnt vmcnt(6)" ::: "memory");
    } else {
      asm volatile("s_waitcnt vmcnt(0)" ::: "memory");
    }
    __builtin_amdgcn_s_barrier();
    if (t < 14) OUT_STAGE((t + 2) % 3, t + 2);

    s16x8 af[2][2], bf[4][2];
    #pragma unroll
    for (int m = 0; m < 2; ++m) {
      af[m][0] = ODSA(L, m, 0);
      af[m][1] = ODSA(L, m, 1);
    }
    #pragma unroll
    for (int n = 0; n < 4; ++n) {
      bf[n][0] = ODSB(L, n, 0);
      bf[n][1] = ODSB(L, n, 1);
    }
    __builtin_amdgcn_s_setprio(1);
    #pragma unroll
    for (int m = 0; m < 2; ++m)
      #pragma unroll
      for (int n = 0; n < 4; ++n) {
        acc[m][n] = mfma32(af[m][0], bf[n][0], acc[m][n]);
        acc[m][n] = mfma32(af[m][1], bf[n][1], acc[m][n]);
      }
    __builtin_amdgcn_s_setprio(0);
  }
#undef OUT_STAGE
#undef ODSA
#undef ODSB

  #pragma unroll
  for (int n = 0; n < 4; ++n) {
    int cg = n0 + wc * 64 + n * 16 + c;
    float bias = bo[cg];
    #pragma unroll
    for (int m = 0; m < 2; ++m) {
      int r = m0 + wr * 32 + m * 16 + g * 4;
      out[(size_t)r * 1024 + cg] = acc[m][n][0] + bias;
      out[(size_t)(r + 1) * 1024 + cg] = acc[m][n][1] + bias;
      out[(size_t)(r + 2) * 1024 + cg] = acc[m][n][2] + bias;
      out[(size_t)(r + 3) * 1024 + cg] = acc[m][n][3] + bias;
    }
  }
}

extern "C" void kernel_launch(void* const* d_in, const int* in_sizes, int n_in,
                              void* d_out, int out_size, void* d_ws, size_t ws_size,
                              hipStream_t stream) {
  (void)in_sizes; (void)n_in; (void)out_size; (void)ws_size;
  const float* x  = (const float*)d_in[0];
  const float* Wq = (const float*)d_in[1];
  const float* bq = (const float*)d_in[2];
  const float* Wk = (const float*)d_in[3];
  const float* bk = (const float*)d_in[4];
  const float* Wv = (const float*)d_in[5];
  const float* bv = (const float*)d_in[6];
  const float* Wo = (const float*)d_in[7];
  const float* bo = (const float*)d_in[8];
  float* out = (float*)d_out;
  char* ws = (char*)d_ws;
  unsigned short* xb  = (unsigned short*)(ws);             // [4096][1024] bf16
  unsigned short* Wt  = (unsigned short*)(ws + 8388608);   // [Wq^T|Wk^T|Wv^T|Wo^T]
  unsigned short* Wot = (unsigned short*)(ws + 14680064);  // = Wt + 3*1048576
  unsigned short* qb  = (unsigned short*)(ws + 16777216);  // pre-scaled q
  unsigned short* kfb = (unsigned short*)(ws + 25165824);  // K fragment-order
  unsigned short* vfb = (unsigned short*)(ws + 33554432);  // V K=32 B-fragment order
  unsigned short* ao  = (unsigned short*)(ws + 41943040);  // [B,S,H,Dh] bf16

  prep<<<2048, 256, 0, stream>>>(x, Wq, Wk, Wv, Wo, xb, Wt);
  qkv_gemm<<<512, 512, 0, stream>>>(xb, Wt, bq, bk, bv, qb, kfb, vfb);
  attn_fwd<<<512, 256, 0, stream>>>(qb, kfb, vfb, ao);
  out_gemm<<<512, 256, 0, stream>>>(ao, Wot, bo, out);
}

// Round 20
// 99.410 us; speedup vs baseline: 1.0615x; 1.0009x over previous
//
#include <hip/hip_runtime.h>
#include <hip/hip_bf16.h>
#include <stdint.h>

using f32x4 = __attribute__((ext_vector_type(4))) float;
using s16x8 = __attribute__((ext_vector_type(8))) short;
using s16x4 = __attribute__((ext_vector_type(4))) short;

__device__ __forceinline__ unsigned short f2bf(float f) {
  union { float f; unsigned int u; } v; v.f = f;
  return (unsigned short)((v.u + 0x7FFFu + ((v.u >> 16) & 1u)) >> 16);
}

__device__ __forceinline__ float exp2_(float x) {
  float r;
  asm("v_exp_f32 %0, %1" : "=v"(r) : "v"(x));
  return r;
}

// pack 2 f32 -> u32 of 2 bf16 (lo=a, hi=b) via single v_cvt_pk_bf16_f32
__device__ __forceinline__ unsigned cvtpk(float a, float b) {
  unsigned r;
  asm("v_cvt_pk_bf16_f32 %0, %1, %2" : "=v"(r) : "v"(a), "v"(b));
  return r;
}

__device__ __forceinline__ short pbf(float f) {
  __hip_bfloat16 h = __float2bfloat16(f);
  return *(short*)&h;
}

#define GLD16(gp, lp) __builtin_amdgcn_global_load_lds( \
    (const __attribute__((address_space(1))) unsigned int*)(uintptr_t)(gp), \
    (__attribute__((address_space(3))) unsigned int*)(uintptr_t)(lp), 16, 0, 0)

__device__ __forceinline__ f32x4 mfma32(s16x8 a, s16x8 b, f32x4 c) {
  return __builtin_amdgcn_mfma_f32_16x16x32_bf16(a, b, c, 0, 0, 0);
}

// ---------------- prep: fused x-convert + 4 weight transposes ----------------
__global__ __launch_bounds__(256)
void prep(const float* __restrict__ x,
          const float* __restrict__ Wq, const float* __restrict__ Wk,
          const float* __restrict__ Wv, const float* __restrict__ Wo,
          unsigned short* __restrict__ xb, unsigned short* __restrict__ Wt) {
  __shared__ float tile[64][65];
  int blk = blockIdx.x;
  int tid = threadIdx.x;
  if (blk < 1024) {
    const float4* xi = (const float4*)x;
    ushort4* xo = (ushort4*)xb;
    #pragma unroll
    for (int j = 0; j < 4; ++j) {
      int i = blk * 1024 + j * 256 + tid;
      float4 v = xi[i];
      ushort4 o;
      o.x = f2bf(v.x); o.y = f2bf(v.y); o.z = f2bf(v.z); o.w = f2bf(v.w);
      xo[i] = o;
    }
  } else {
    int wid = blk - 1024;
    int which = wid >> 8, t = wid & 255;
    const float* W = (which == 0) ? Wq : (which == 1) ? Wk : (which == 2) ? Wv : Wo;
    unsigned short* dst = Wt + (size_t)which * 1048576;
    int k0 = (t & 15) * 64, n0 = (t >> 4) * 64;
    int tx = tid & 63, ty = tid >> 6;
    #pragma unroll
    for (int j = 0; j < 64; j += 4)
      tile[ty + j][tx] = W[(size_t)(k0 + ty + j) * 1024 + n0 + tx];
    __syncthreads();
    #pragma unroll
    for (int j = 0; j < 64; j += 4)
      dst[(size_t)(n0 + ty + j) * 1024 + k0 + tx] = f2bf(tile[tx][ty + j]);
  }
}

// ---------------- fused QKV GEMM: 128x192 tile, 8 waves, BK=64 (R17) ---------
__global__ __launch_bounds__(512, 4)
void qkv_gemm(const unsigned short* __restrict__ A,
              const unsigned short* __restrict__ Bt,
              const float* __restrict__ bq, const float* __restrict__ bk,
              const float* __restrict__ bv,
              unsigned short* __restrict__ qo, unsigned short* __restrict__ kf,
              unsigned short* __restrict__ vf) {
  __shared__ unsigned short lds2[2][20480];   // per buf: A 0..8191, B 8192..20479
  int orig = blockIdx.x;                      // 512 wgs
  int wg = (orig & 7) * 64 + (orig >> 3);
  int bm = wg >> 4, bn = wg & 15;
  int m0 = bm << 7;
  int n0 = bn * 192;
  int tid = threadIdx.x;
  int w = tid >> 6, ln = tid & 63;
  int g = ln >> 4, c = ln & 15;
  int wm = w >> 2, wn = w & 3;                // 2M x 4N waves; wave = 64x48

  int rrs = tid >> 3;
  int lcol = (((tid & 7) ^ ((tid >> 3) & 7)) << 4);
  const char* pA = (const char*)A + (size_t)(m0 + rrs) * 2048 + lcol;
  const char* pB = (const char*)Bt + (size_t)(n0 + rrs) * 2048 + lcol;
  int woff = w * 1024;

#define QKV_STAGE(buf, kt)                                                     \
  {                                                                            \
    char* db = (char*)&lds2[buf][0];                                           \
    _Pragma("unroll")                                                          \
    for (int s = 0; s < 2; ++s)                                                \
      GLD16(pA + (size_t)s * 131072 + (kt) * 128, db + s * 8192 + woff);       \
    _Pragma("unroll")                                                          \
    for (int s = 0; s < 3; ++s)                                                \
      GLD16(pB + (size_t)s * 131072 + (kt) * 128,                              \
            db + 16384 + s * 8192 + woff);                                     \
  }

  int cs = (c & 7) << 4;
#define DSFA(LA, mi, kk)                                                       \
  (*(const s16x8*)&(LA)[((mi) * 16 + c) * 64 +                                 \
                        ((((kk) * 64 + g * 16) ^ cs) >> 1)])
#define DSFB(LB, ni, kk)                                                       \
  (*(const s16x8*)&(LB)[((wn * 48 + (ni) * 16) >> 6) * 4096 +                  \
                        (((wn * 48 + (ni) * 16) & 63) + c) * 64 +              \
                        ((((kk) * 64 + g * 16) ^ cs) >> 1)])

  f32x4 acc[4][3];
  f32x4 zero = {0.f, 0.f, 0.f, 0.f};
  #pragma unroll
  for (int mi = 0; mi < 4; ++mi)
    #pragma unroll
    for (int ni = 0; ni < 3; ++ni) acc[mi][ni] = zero;

  QKV_STAGE(0, 0);
  asm volatile("s_waitcnt vmcnt(0)" ::: "memory");
  __builtin_amdgcn_s_barrier();

  for (int kt = 0; kt < 16; ++kt) {
    int bsel = kt & 1;
    const unsigned short* LA = &lds2[bsel][wm * 4096];
    const unsigned short* LB = &lds2[bsel][8192];
    if (kt < 15) QKV_STAGE(bsel ^ 1, kt + 1);

    s16x8 bfr[3][2];
    #pragma unroll
    for (int ni = 0; ni < 3; ++ni) {
      bfr[ni][0] = DSFB(LB, ni, 0);
      bfr[ni][1] = DSFB(LB, ni, 1);
    }
    s16x8 a[4][2];
    #pragma unroll
    for (int mi = 0; mi < 4; ++mi) {
      a[mi][0] = DSFA(LA, mi, 0);
      a[mi][1] = DSFA(LA, mi, 1);
    }
    __builtin_amdgcn_s_setprio(1);
    #pragma unroll
    for (int mi = 0; mi < 4; ++mi)
      #pragma unroll
      for (int ni = 0; ni < 3; ++ni) {
        acc[mi][ni] = mfma32(a[mi][0], bfr[ni][0], acc[mi][ni]);
        acc[mi][ni] = mfma32(a[mi][1], bfr[ni][1], acc[mi][ni]);
      }
    __builtin_amdgcn_s_setprio(0);

    asm volatile("s_waitcnt vmcnt(0)" ::: "memory");
    __builtin_amdgcn_s_barrier();
  }
#undef QKV_STAGE
#undef DSFA
#undef DSFB

  #pragma unroll
  for (int ni = 0; ni < 3; ++ni) {
    int cg = n0 + wn * 48 + ni * 16 + c;    // 0..3071
    int p = cg >> 10;                        // 0=q 1=k 2=v
    int d = cg & 1023;
    int hh = d >> 6, dh = d & 63;
    const float* bp = (p == 0) ? bq : (p == 1) ? bk : bv;
    float bias = bp[d];
    #pragma unroll
    for (int mi = 0; mi < 4; ++mi) {
      int r = m0 + wm * 64 + mi * 16 + g * 4;  // rows r..r+3 (e=0..3)
      int b2 = r >> 11, s = r & 2047;
      size_t pv = (size_t)((b2 << 4) + hh);
      if (p == 2) {
        int ch = s >> 5;
        int l16 = ((s >> 3) & 3) * 16 + (dh & 15);
        int jo = s & 7;
        ushort4 pk;
        pk.x = f2bf(acc[mi][ni][0] + bias);
        pk.y = f2bf(acc[mi][ni][1] + bias);
        pk.z = f2bf(acc[mi][ni][2] + bias);
        pk.w = f2bf(acc[mi][ni][3] + bias);
        *(ushort4*)&vf[pv * 131072 +
                       (size_t)((ch * 4 + (dh >> 4)) * 64 + l16) * 8 + jo] = pk;
      } else if (p == 1) {
        int T = s >> 4;
        int h2 = dh >> 5, gp = (dh >> 3) & 3, j = dh & 7;
        unsigned short* kd = kf + pv * 131072 + T * 1024 + h2 * 512 +
                             (gp * 16 + (s & 15)) * 8 + j;
        kd[0]  = f2bf(acc[mi][ni][0] + bias);
        kd[8]  = f2bf(acc[mi][ni][1] + bias);
        kd[16] = f2bf(acc[mi][ni][2] + bias);
        kd[24] = f2bf(acc[mi][ni][3] + bias);
      } else {
        const float sc = 0.180336880111120f;  // 1/8 * log2(e)
        size_t base = (pv * 2048 + s) * 64 + dh;
        qo[base]       = f2bf((acc[mi][ni][0] + bias) * sc);
        qo[base + 64]  = f2bf((acc[mi][ni][1] + bias) * sc);
        qo[base + 128] = f2bf((acc[mi][ni][2] + bias) * sc);
        qo[base + 192] = f2bf((acc[mi][ni][3] + bias) * sc);
      }
    }
  }
}

// ---------------- flash attention (R14: quad-buffer ring, 1 barrier/iter) ----
__global__ __launch_bounds__(256, 2)
void attn_fwd(const unsigned short* __restrict__ q,
              const unsigned short* __restrict__ kfb,
              const unsigned short* __restrict__ vfb,
              unsigned short* __restrict__ ao) {
  __shared__ unsigned short ldsKV[4][8192];  // ring: per buf K 0..4095, V 4096..8191
  __shared__ unsigned short ldsP[4][2048];   // wave-private P scratch (4KB/wave)
  int orig = blockIdx.x;                    // 512 wgs
  int wg = (orig & 7) * 64 + (orig >> 3);   // XCD-contiguous
  int pair = wg >> 4, qt = wg & 15;
  int tid = threadIdx.x;
  int w = tid >> 6, ln = tid & 63;
  int g = ln >> 4, c = ln & 15;
  int q0 = qt * 128 + w * 32;
  const unsigned short* qp = q + (size_t)pair * 131072;
  const char* kbase = (const char*)(kfb + (size_t)pair * 131072);
  const char* vbase = (const char*)(vfb + (size_t)pair * 131072);

  const char* ssrc = ((w < 2) ? kbase : vbase) + (w & 1) * 4096;
  int dsto = (w >= 2 ? 8192 : 0) + (w & 1) * 4096;

  unsigned short* Pw = &ldsP[w][0];
  int pwbase = (g >> 1) * 128 + c * 8 + (g & 1) * 4;

  s16x8 qf[2][2];
  #pragma unroll
  for (int j = 0; j < 2; ++j)
    #pragma unroll
    for (int h = 0; h < 2; ++h)
      qf[j][h] = *(const s16x8*)&qp[(q0 + j * 16 + c) * 64 + h * 32 + g * 8];

  f32x4 acc[2][4];
  f32x4 zero = {0.f, 0.f, 0.f, 0.f};
  #pragma unroll
  for (int j = 0; j < 2; ++j)
    #pragma unroll
    for (int dt = 0; dt < 4; ++dt) acc[j][dt] = zero;
  float l0 = 0.f, l1 = 0.f;

  #pragma unroll
  for (int jj = 0; jj < 4; ++jj)
    GLD16(ssrc + jj * 1024 + ln * 16, (char*)&ldsKV[0][0] + dsto + jj * 1024);

  const unsigned short* L0 = ldsKV[0];
  const unsigned short* L1 = ldsKV[1];
  const unsigned short* L2 = ldsKV[2];
  const unsigned short* L3 = ldsKV[3];

#define ATTN_ITER(T, LC, LP, LN)                                               \
  {                                                                            \
    if ((T) < 31) {                                                            \
      const char* s2 = ssrc + (size_t)((T) + 1) * 8192;                        \
      char* d2 = (char*)(LN) + dsto;                                           \
      _Pragma("unroll")                                                        \
      for (int jj = 0; jj < 4; ++jj)                                           \
        GLD16(s2 + jj * 1024 + ln * 16, d2 + jj * 1024);                       \
      asm volatile("s_waitcnt vmcnt(4)" ::: "memory");                         \
    } else {                                                                   \
      asm volatile("s_waitcnt vmcnt(0)" ::: "memory");                         \
    }                                                                          \
    __builtin_amdgcn_s_barrier();                                              \
    s16x8 kc[4][2];                                                            \
    _Pragma("unroll")                                                          \
    for (int kt = 0; kt < 4; ++kt) {                                           \
      kc[kt][0] = *(const s16x8*)&(LC)[kt * 1024 + ln * 8];                    \
      kc[kt][1] = *(const s16x8*)&(LC)[kt * 1024 + 512 + ln * 8];              \
    }                                                                          \
    f32x4 st[4][2];                                                            \
    __builtin_amdgcn_s_setprio(1);                                             \
    _Pragma("unroll")                                                          \
    for (int kt = 0; kt < 4; ++kt)                                             \
      _Pragma("unroll")                                                        \
      for (int j = 0; j < 2; ++j) {                                            \
        f32x4 t2 = zero;                                                       \
        t2 = mfma32(kc[kt][0], qf[j][0], t2);                                  \
        t2 = mfma32(kc[kt][1], qf[j][1], t2);                                  \
        st[kt][j] = t2;                                                        \
      }                                                                        \
    __builtin_amdgcn_s_setprio(0);                                             \
    if ((T) > 0) {                                                             \
      s16x8 pa00 = *(const s16x8*)&Pw[ln * 8];                                 \
      s16x8 pa01 = *(const s16x8*)&Pw[512 + ln * 8];                           \
      s16x8 pa10 = *(const s16x8*)&Pw[1024 + ln * 8];                          \
      s16x8 pa11 = *(const s16x8*)&Pw[1536 + ln * 8];                          \
      __builtin_amdgcn_s_setprio(1);                                           \
      _Pragma("unroll")                                                        \
      for (int m = 0; m < 2; ++m)                                              \
        _Pragma("unroll")                                                      \
        for (int dt = 0; dt < 4; ++dt) {                                       \
          s16x8 vv = *(const s16x8*)&(LP)[4096 + m * 2048 + dt * 512 + ln * 8];\
          acc[0][dt] = mfma32(m ? pa01 : pa00, vv, acc[0][dt]);                \
          acc[1][dt] = mfma32(m ? pa11 : pa10, vv, acc[1][dt]);                \
        }                                                                      \
      __builtin_amdgcn_s_setprio(0);                                           \
    }                                                                          \
    _Pragma("unroll")                                                          \
    for (int kt = 0; kt < 4; ++kt) {                                           \
      float p00 = exp2_(st[kt][0][0]), p01 = exp2_(st[kt][0][1]);              \
      float p02 = exp2_(st[kt][0][2]), p03 = exp2_(st[kt][0][3]);              \
      float p10 = exp2_(st[kt][1][0]), p11 = exp2_(st[kt][1][1]);              \
      float p12 = exp2_(st[kt][1][2]), p13 = exp2_(st[kt][1][3]);              \
      l0 += (p00 + p01) + (p02 + p03);                                         \
      l1 += (p10 + p11) + (p12 + p13);                                         \
      int wa = (kt >> 1) * 512 + (kt & 1) * 256 + pwbase;                      \
      uint2 w0; w0.x = cvtpk(p00, p01); w0.y = cvtpk(p02, p03);                \
      *(uint2*)&Pw[wa] = w0;                                                   \
      uint2 w1; w1.x = cvtpk(p10, p11); w1.y = cvtpk(p12, p13);                \
      *(uint2*)&Pw[1024 + wa] = w1;                                            \
    }                                                                          \
  }

  for (int t = 0; t < 32; t += 4) {
    ATTN_ITER(t,     L0, L3, L1);
    ATTN_ITER(t + 1, L1, L0, L2);
    ATTN_ITER(t + 2, L2, L1, L3);
    ATTN_ITER(t + 3, L3, L2, L0);
  }
#undef ATTN_ITER

  {
    s16x8 pa00 = *(const s16x8*)&Pw[ln * 8];
    s16x8 pa01 = *(const s16x8*)&Pw[512 + ln * 8];
    s16x8 pa10 = *(const s16x8*)&Pw[1024 + ln * 8];
    s16x8 pa11 = *(const s16x8*)&Pw[1536 + ln * 8];
    __builtin_amdgcn_s_setprio(1);
    #pragma unroll
    for (int m = 0; m < 2; ++m)
      #pragma unroll
      for (int dt = 0; dt < 4; ++dt) {
        s16x8 vv = *(const s16x8*)&L3[4096 + m * 2048 + dt * 512 + ln * 8];
        acc[0][dt] = mfma32(m ? pa01 : pa00, vv, acc[0][dt]);
        acc[1][dt] = mfma32(m ? pa11 : pa10, vv, acc[1][dt]);
      }
    __builtin_amdgcn_s_setprio(0);
  }

  l0 += __shfl_xor(l0, 16); l0 += __shfl_xor(l0, 32);
  l1 += __shfl_xor(l1, 16); l1 += __shfl_xor(l1, 32);
  float li0 = 1.f / l0, li1 = 1.f / l1;
  int b = pair >> 4, hh = pair & 15;
  #pragma unroll
  for (int e = 0; e < 4; ++e) {
    float i0 = __shfl(li0, g * 4 + e);
    float i1 = __shfl(li1, g * 4 + e);
    size_t r0 = ((size_t)(b * 2048 + q0 + g * 4 + e) * 16 + hh) * 64;
    size_t r1 = ((size_t)(b * 2048 + q0 + 16 + g * 4 + e) * 16 + hh) * 64;
    #pragma unroll
    for (int dt = 0; dt < 4; ++dt) {
      ao[r0 + dt * 16 + c] = (unsigned short)pbf(acc[0][dt][e] * i0);
      ao[r1 + dt * 16 + c] = (unsigned short)pbf(acc[1][dt][e] * i1);
    }
  }
}

// ---------------- output GEMM: 64x128 tile, BK=64, RING-3, swizzled (R16) ----
__global__ __launch_bounds__(256, 2)
void out_gemm(const unsigned short* __restrict__ A,
              const unsigned short* __restrict__ Bt,
              const float* __restrict__ bo, float* __restrict__ out) {
  __shared__ unsigned short lds[3][12288];  // per buf: A [64][64] @0, B [128][64] @4096
  int orig = blockIdx.x;                    // 512 wgs
  int wg = (orig & 7) * 64 + (orig >> 3);
  int bm = wg >> 3, bn = wg & 7;
  int m0 = bm << 6, n0 = bn << 7;
  int tid = threadIdx.x;
  int w = tid >> 6, ln = tid & 63;
  int g = ln >> 4, c = ln & 15;
  int wr = w >> 1, wc = w & 1;

  int rrs = tid >> 3;                       // 0..31
  int lcol = (((tid & 7) ^ ((tid >> 3) & 7)) << 4);
  const char* pA = (const char*)A + (size_t)(m0 + rrs) * 2048 + lcol;
  const char* pB = (const char*)Bt + (size_t)(n0 + rrs) * 2048 + lcol;
  int woff = w * 1024;

#define OUT_STAGE(buf, kt)                                                     \
  {                                                                            \
    char* db = (char*)&lds[buf][0];                                            \
    _Pragma("unroll")                                                          \
    for (int s = 0; s < 2; ++s)                                                \
      GLD16(pA + (size_t)s * 65536 + (kt) * 128, db + s * 4096 + woff);        \
    _Pragma("unroll")                                                          \
    for (int s = 0; s < 4; ++s)                                                \
      GLD16(pB + (size_t)s * 65536 + (kt) * 128, db + 8192 + s * 4096 + woff); \
  }

  int cs = (c & 7) << 4;
#define ODSA(L, mi, kk)                                                        \
  (*(const s16x8*)&(L)[(wr * 32 + (mi) * 16 + c) * 64 +                        \
                       ((((kk) * 64 + g * 16) ^ cs) >> 1)])
#define ODSB(L, ni, kk)                                                        \
  (*(const s16x8*)&(L)[4096 + (wc * 64 + (ni) * 16 + c) * 64 +                 \
                       ((((kk) * 64 + g * 16) ^ cs) >> 1)])

  f32x4 acc[2][4];
  f32x4 zero = {0.f, 0.f, 0.f, 0.f};
  #pragma unroll
  for (int m = 0; m < 2; ++m)
    #pragma unroll
    for (int n = 0; n < 4; ++n) acc[m][n] = zero;

  OUT_STAGE(0, 0);
  OUT_STAGE(1, 1);

  for (int t = 0; t < 16; ++t) {
    int bsel = t % 3;
    const unsigned short* L = &lds[bsel][0];
    if (t < 15) {
      asm volatile("s_waitcnt vmcnt(6)" ::: "memory");
    } else {
      asm volatile("s_waitcnt vmcnt(0)" ::: "memory");
    }
    __builtin_amdgcn_s_barrier();
    if (t < 14) OUT_STAGE((t + 2) % 3, t + 2);

    s16x8 af[2][2], bf[4][2];
    #pragma unroll
    for (int m = 0; m < 2; ++m) {
      af[m][0] = ODSA(L, m, 0);
      af[m][1] = ODSA(L, m, 1);
    }
    #pragma unroll
    for (int n = 0; n < 4; ++n) {
      bf[n][0] = ODSB(L, n, 0);
      bf[n][1] = ODSB(L, n, 1);
    }
    __builtin_amdgcn_s_setprio(1);
    #pragma unroll
    for (int m = 0; m < 2; ++m)
      #pragma unroll
      for (int n = 0; n < 4; ++n) {
        acc[m][n] = mfma32(af[m][0], bf[n][0], acc[m][n]);
        acc[m][n] = mfma32(af[m][1], bf[n][1], acc[m][n]);
      }
    __builtin_amdgcn_s_setprio(0);
  }
#undef OUT_STAGE
#undef ODSA
#undef ODSB

  #pragma unroll
  for (int n = 0; n < 4; ++n) {
    int cg = n0 + wc * 64 + n * 16 + c;
    float bias = bo[cg];
    #pragma unroll
    for (int m = 0; m < 2; ++m) {
      int r = m0 + wr * 32 + m * 16 + g * 4;
      out[(size_t)r * 1024 + cg] = acc[m][n][0] + bias;
      out[(size_t)(r + 1) * 1024 + cg] = acc[m][n][1] + bias;
      out[(size_t)(r + 2) * 1024 + cg] = acc[m][n][2] + bias;
      out[(size_t)(r + 3) * 1024 + cg] = acc[m][n][3] + bias;
    }
  }
}

extern "C" void kernel_launch(void* const* d_in, const int* in_sizes, int n_in,
                              void* d_out, int out_size, void* d_ws, size_t ws_size,
                              hipStream_t stream) {
  (void)in_sizes; (void)n_in; (void)out_size; (void)ws_size;
  const float* x  = (const float*)d_in[0];
  const float* Wq = (const float*)d_in[1];
  const float* bq = (const float*)d_in[2];
  const float* Wk = (const float*)d_in[3];
  const float* bk = (const float*)d_in[4];
  const float* Wv = (const float*)d_in[5];
  const float* bv = (const float*)d_in[6];
  const float* Wo = (const float*)d_in[7];
  const float* bo = (const float*)d_in[8];
  float* out = (float*)d_out;
  char* ws = (char*)d_ws;
  unsigned short* xb  = (unsigned short*)(ws);             // [4096][1024] bf16
  unsigned short* Wt  = (unsigned short*)(ws + 8388608);   // [Wq^T|Wk^T|Wv^T|Wo^T]
  unsigned short* Wot = (unsigned short*)(ws + 14680064);  // = Wt + 3*1048576
  unsigned short* qb  = (unsigned short*)(ws + 16777216);  // pre-scaled q
  unsigned short* kfb = (unsigned short*)(ws + 25165824);  // K fragment-order
  unsigned short* vfb = (unsigned short*)(ws + 33554432);  // V K=32 B-fragment order
  unsigned short* ao  = (unsigned short*)(ws + 41943040);  // [B,S,H,Dh] bf16

  prep<<<2048, 256, 0, stream>>>(x, Wq, Wk, Wv, Wo, xb, Wt);
  qkv_gemm<<<512, 512, 0, stream>>>(xb, Wt, bq, bk, bv, qb, kfb, vfb);
  attn_fwd<<<512, 256, 0, stream>>>(qb, kfb, vfb, ao);
  out_gemm<<<512, 256, 0, stream>>>(ao, Wot, bo, out);
}